// Round 13
// baseline (318.503 us; speedup 1.0000x reference)
//
#include <hip/hip_runtime.h>
#include <hip/hip_bf16.h>
#include <math.h>

typedef unsigned short u16;
typedef unsigned int u32;
typedef unsigned char u8;
typedef __attribute__((ext_vector_type(8))) short short8;
typedef __attribute__((ext_vector_type(4))) float f32x4;
typedef __attribute__((ext_vector_type(2))) float f32x2;

#define NB 128  // bucket slots (actual buckets = ceil(n/512) = 98 for n=50000)

static __device__ __forceinline__ u16 f2bf(float f) {
    u32 u = __float_as_uint(f);
    u32 r = (u + 0x7fffu + ((u >> 16) & 1u)) >> 16;
    return (u16)r;
}
static __device__ __forceinline__ float bl(u32 u) { return __uint_as_float(u << 16); }
static __device__ __forceinline__ float bh(u32 u) { return __uint_as_float(u & 0xffff0000u); }

// ---------------- CSR build (bucket-first, no per-node global atomics) --------

__global__ __launch_bounds__(256) void k_bhist(const int* __restrict__ dst, int E,
                                               int* __restrict__ bcnt) {
    __shared__ int lh[NB];
    int tid = threadIdx.x;
    int base = blockIdx.x * 2048;
    for (int i = tid; i < NB; i += 256) lh[i] = 0;
    __syncthreads();
    int cnt = min(2048, E - base);
    #pragma unroll
    for (int k = 0; k < 8; k++) {
        int i = tid + k * 256;
        if (i < cnt) atomicAdd(&lh[dst[base + i] >> 9], 1);
    }
    __syncthreads();
    for (int i = tid; i < NB; i += 256) {
        int c = lh[i];
        if (c) atomicAdd(&bcnt[i], c);
    }
}

__global__ void k_bscan(const int* __restrict__ bcnt, int* __restrict__ bbase,
                        int* __restrict__ bcur, int* __restrict__ ptrN, int nb) {
    __shared__ int sh[NB];
    int t = threadIdx.x;  // 128
    int v = (t < nb) ? bcnt[t] : 0;
    sh[t] = v;
    __syncthreads();
    for (int off = 1; off < NB; off <<= 1) {
        int val = sh[t];
        int add = (t >= off) ? sh[t - off] : 0;
        __syncthreads();
        sh[t] = val + add;
        __syncthreads();
    }
    int excl = sh[t] - v;
    if (t <= nb) bbase[t] = excl;
    if (t < nb) bcur[t] = excl;
    if (t == nb) *ptrN = excl;   // total = E
}

__global__ __launch_bounds__(256) void k_part(const int* __restrict__ src,
                                              const int* __restrict__ dst, int E,
                                              int* __restrict__ bcur,
                                              u32* __restrict__ part) {
    __shared__ int lh[NB];
    __shared__ int gb[NB];
    int tid = threadIdx.x;
    int base = blockIdx.x * 2048;
    for (int i = tid; i < NB; i += 256) lh[i] = 0;
    __syncthreads();
    int cnt = min(2048, E - base);
    int bkt[8], rank[8]; u32 pk[8];
    #pragma unroll
    for (int k = 0; k < 8; k++) {
        int i = tid + k * 256;
        if (i < cnt) {
            int s = src[base + i], d = dst[base + i];
            int b = d >> 9;
            bkt[k] = b;
            pk[k] = ((u32)(d & 511) << 16) | (u32)s;
            rank[k] = atomicAdd(&lh[b], 1);
        } else bkt[k] = -1;
    }
    __syncthreads();
    for (int i = tid; i < NB; i += 256) {
        int c = lh[i];
        gb[i] = c ? atomicAdd(&bcur[i], c) : 0;
    }
    __syncthreads();
    #pragma unroll
    for (int k = 0; k < 8; k++)
        if (bkt[k] >= 0) part[gb[bkt[k]] + rank[k]] = pk[k];
}

// per-bucket: hist of dstLow9 + in-LDS scan -> ptr; then scatter slice -> csr16
__global__ __launch_bounds__(256) void k_dhs(const u32* __restrict__ part,
                                             const int* __restrict__ bbase,
                                             int* __restrict__ ptrArr,
                                             u16* __restrict__ csr, int n) {
    __shared__ int hist[512];
    __shared__ int tsum[256];
    int b = blockIdx.x;
    int t = threadIdx.x;
    int lo = bbase[b], hi = bbase[b + 1];
    hist[t] = 0; hist[t + 256] = 0;
    __syncthreads();
    for (int i = lo + t; i < hi; i += 256)
        atomicAdd(&hist[(part[i] >> 16) & 511], 1);
    __syncthreads();
    int v0 = hist[2 * t], v1 = hist[2 * t + 1];
    tsum[t] = v0 + v1;
    __syncthreads();
    for (int off = 1; off < 256; off <<= 1) {
        int val = tsum[t];
        int add = (t >= off) ? tsum[t - off] : 0;
        __syncthreads();
        tsum[t] = val + add;
        __syncthreads();
    }
    int basep = lo + ((t == 0) ? 0 : tsum[t - 1]);
    int i0 = (b << 9) + 2 * t;
    if (i0 < n)     ptrArr[i0] = basep;
    if (i0 + 1 < n) ptrArr[i0 + 1] = basep + v0;
    __syncthreads();
    hist[2 * t] = basep;             // cursors
    hist[2 * t + 1] = basep + v0;
    __syncthreads();
    for (int i = lo + t; i < hi; i += 256) {
        u32 pk = part[i];
        int pos = atomicAdd(&hist[(pk >> 16) & 511], 1);
        csr[pos] = (u16)(pk & 0xffffu);
    }
}

// ---------------- weight prep (fragment-major bf16 B tables) ----------------
// BF1[t<9][kb<16][lane<64] = 8 u16: B_mat[t*16+(lane&15)][kb*32+(lane>>4)*8 + i]
__global__ void k_build_BF1(const float* __restrict__ Ws, const float* __restrict__ Wd,
                            const float* __restrict__ Wd2, const float* __restrict__ as_,
                            const float* __restrict__ ad, const float* __restrict__ ad2,
                            u16* __restrict__ BF) {
    int tid = blockIdx.x * blockDim.x + threadIdx.x;
    if (tid >= 9 * 16 * 64) return;
    int t = tid >> 10;                // /(16*64)
    int kb = (tid >> 6) & 15;
    int lane = tid & 63;
    int nn = t * 16 + (lane & 15);
    int kbase = kb * 32 + (lane >> 4) * 8;
    u16 outv[8];
    #pragma unroll
    for (int i = 0; i < 8; i++) {
        int k = kbase + i;
        float v = 0.f;
        if (k < 500) {
            if (nn < 128) v = Ws[k * 128 + nn];
            else if (nn < 140) {
                int q = nn - 128; int h = q & 3;
                const float* W; const float* a;
                if (q < 4)      { W = Ws;  a = as_; }
                else if (q < 8) { W = Wd;  a = ad;  }
                else            { W = Wd2; a = ad2; }
                float s = 0.f;
                #pragma unroll 8
                for (int c = 0; c < 32; c++) s += W[k * 128 + h * 32 + c] * a[h * 32 + c];
                v = s;
            }
        }
        outv[i] = f2bf(v);
    }
    *(uint4*)&BF[(size_t)tid * 8] = *(uint4*)outv;
}

// BF2[t<3][kb<8][lane<64]: B_mat[t*16+(lane&15)][kb*32+(lane>>4)*8+i], k<256
__global__ void k_build_BF2(const float* __restrict__ Ws, const float* __restrict__ Wd,
                            const float* __restrict__ Wd2, const float* __restrict__ as_,
                            const float* __restrict__ ad, const float* __restrict__ ad2,
                            u16* __restrict__ BF) {
    int tid = blockIdx.x * blockDim.x + threadIdx.x;
    if (tid >= 3 * 8 * 64) return;
    int t = tid >> 9;                 // /(8*64)
    int kb = (tid >> 6) & 7;
    int lane = tid & 63;
    int nn = t * 16 + (lane & 15);
    int kbase = kb * 32 + (lane >> 4) * 8;
    u16 outv[8];
    #pragma unroll
    for (int i = 0; i < 8; i++) {
        int k = kbase + i;
        float v = 0.f;
        if (nn < 40) v = Ws[k * 40 + nn];
        else if (nn < 43) {
            const float* a = (nn == 40) ? as_ : (nn == 41) ? ad : ad2;
            const float* W = Ws;
            if (nn == 41) W = Wd; else if (nn == 42) W = Wd2;
            float s = 0.f;
            #pragma unroll 8
            for (int c = 0; c < 40; c++) s += W[k * 40 + c] * a[c];
            v = s;
        }
        outv[i] = f2bf(v);
    }
    *(uint4*)&BF[(size_t)tid * 8] = *(uint4*)outv;
}

// ---------------- MFMA GEMM layer 1: barrier-free, unrolled-pipelined ---------
// kb 0..14 are branch-free (kg+8 <= 488 < 500); only kb=15 needs element guards.
// #pragma unroll 4 exposes ~44 independent loads per window for latency hiding.
__global__ __launch_bounds__(256) void k_mgemm1(const float* __restrict__ A,
                                                const uint4* __restrict__ BF,
                                                u8* __restrict__ xb,
                                                float* __restrict__ alb, int M) {
    int lane = threadIdx.x & 63;
    int wid = (blockIdx.x * 256 + threadIdx.x) >> 6;
    int nw = (M + 15) >> 4;
    if (wid >= nw) return;
    int l15 = lane & 15, k8 = lane >> 4;
    int rowBlk = wid * 16;
    int arow = rowBlk + l15;
    bool rowOK = arow < M;                  // always true when M % 16 == 0
    const float* Ap0 = A + (size_t)arow * 500;

    f32x4 acc[9];
    #pragma unroll
    for (int t = 0; t < 9; t++) acc[t] = (f32x4){0.f, 0.f, 0.f, 0.f};

    const uint4* Bp0 = BF + lane;

    #pragma unroll 4
    for (int kb = 0; kb < 15; kb++) {
        int kg = kb * 32 + k8 * 8;          // kg+8 <= 488 < 500: no k guard
        float4 p0, p1;
        if (rowOK) {
            p0 = *(const float4*)(Ap0 + kg);
            p1 = *(const float4*)(Ap0 + kg + 4);
        } else {
            p0 = (float4){0.f, 0.f, 0.f, 0.f};
            p1 = (float4){0.f, 0.f, 0.f, 0.f};
        }
        short8 af;
        ((u32*)&af)[0] = (u32)f2bf(p0.x) | ((u32)f2bf(p0.y) << 16);
        ((u32*)&af)[1] = (u32)f2bf(p0.z) | ((u32)f2bf(p0.w) << 16);
        ((u32*)&af)[2] = (u32)f2bf(p1.x) | ((u32)f2bf(p1.y) << 16);
        ((u32*)&af)[3] = (u32)f2bf(p1.z) | ((u32)f2bf(p1.w) << 16);
        const uint4* Bp = Bp0 + (size_t)kb * 64;
        #pragma unroll
        for (int t = 0; t < 9; t++) {
            uint4 braw = Bp[(size_t)t * 16 * 64];
            acc[t] = __builtin_amdgcn_mfma_f32_16x16x32_bf16(af, *(const short8*)&braw,
                                                             acc[t], 0, 0, 0);
        }
    }
    {   // kb = 15 tail: k = 480 + k8*8 + i, guard k < 500 per element
        int kg = 480 + k8 * 8;
        float v[8];
        #pragma unroll
        for (int i = 0; i < 8; i++)
            v[i] = (rowOK && kg + i < 500) ? Ap0[kg + i] : 0.f;
        short8 af;
        ((u32*)&af)[0] = (u32)f2bf(v[0]) | ((u32)f2bf(v[1]) << 16);
        ((u32*)&af)[1] = (u32)f2bf(v[2]) | ((u32)f2bf(v[3]) << 16);
        ((u32*)&af)[2] = (u32)f2bf(v[4]) | ((u32)f2bf(v[5]) << 16);
        ((u32*)&af)[3] = (u32)f2bf(v[6]) | ((u32)f2bf(v[7]) << 16);
        const uint4* Bp = Bp0 + (size_t)15 * 64;
        #pragma unroll
        for (int t = 0; t < 9; t++) {
            uint4 braw = Bp[(size_t)t * 16 * 64];
            acc[t] = __builtin_amdgcn_mfma_f32_16x16x32_bf16(af, *(const short8*)&braw,
                                                             acc[t], 0, 0, 0);
        }
    }
    #pragma unroll
    for (int t = 0; t < 9; t++) {
        #pragma unroll
        for (int rr = 0; rr < 4; rr++) {
            int grow = rowBlk + k8 * 4 + rr;
            if (grow < M) {
                if (t < 8) {
                    u32 p8 = __builtin_amdgcn_cvt_pk_fp8_f32(acc[t][rr], acc[t][rr], 0, false);
                    xb[(size_t)grow * 128 + t * 16 + l15] = (u8)(p8 & 0xffu);
                } else if (l15 < 12) {
                    alb[(size_t)grow * 16 + l15] = acc[t][rr];
                }
            }
        }
    }
}

// ---------------- MFMA GEMM layer 2: barrier-free, fully unrolled -------------
__global__ __launch_bounds__(256) void k_mgemm2(const u16* __restrict__ A,
                                                const uint4* __restrict__ BF,
                                                u16* __restrict__ xb,
                                                float* __restrict__ alb, int M) {
    int lane = threadIdx.x & 63;
    int wid = (blockIdx.x * 256 + threadIdx.x) >> 6;
    int nw = (M + 15) >> 4;
    if (wid >= nw) return;
    int l15 = lane & 15, k8 = lane >> 4;
    int rowBlk = wid * 16;
    int arow = rowBlk + l15;
    bool rowOK = arow < M;
    const u16* Ap0 = A + (size_t)arow * 256;

    f32x4 acc[3];
    #pragma unroll
    for (int t = 0; t < 3; t++) acc[t] = (f32x4){0.f, 0.f, 0.f, 0.f};

    #pragma unroll
    for (int kb = 0; kb < 8; kb++) {
        short8 af = {0, 0, 0, 0, 0, 0, 0, 0};
        if (rowOK) af = *(const short8*)(Ap0 + kb * 32 + k8 * 8);
        const uint4* Bp = BF + (size_t)kb * 64 + lane;
        #pragma unroll
        for (int t = 0; t < 3; t++) {
            uint4 braw = Bp[(size_t)t * 8 * 64];
            acc[t] = __builtin_amdgcn_mfma_f32_16x16x32_bf16(af, *(const short8*)&braw,
                                                             acc[t], 0, 0, 0);
        }
    }
    #pragma unroll
    for (int t = 0; t < 3; t++) {
        #pragma unroll
        for (int rr = 0; rr < 4; rr++) {
            int grow = rowBlk + k8 * 4 + rr;
            if (grow < M) {
                int col = t * 16 + l15;
                if (col < 40) xb[(size_t)grow * 40 + col] = f2bf(acc[t][rr]);
                else if (col < 43) alb[(size_t)grow * 4 + (col - 40)] = acc[t][rr];
            }
        }
    }
}

// ---------------- layer-1 propagate (fp8 gather) ----------------
__global__ __launch_bounds__(256) void k_prop1(const int* __restrict__ ptr, const u16* __restrict__ csr,
                                               const float* __restrict__ al, int doff,
                                               const u32* __restrict__ xbv,
                                               u16* __restrict__ out, int n) {
    __shared__ int sbuf[4][64];
    __shared__ __align__(16) float wbuf[4][64][4];
    int tid = threadIdx.x;
    int wv = tid >> 6, lane = tid & 63;
    int wid = (blockIdx.x * 256 + tid) >> 6;
    if (wid >= n) return;
    int b = ptr[wid], e = ptr[wid + 1];
    float4 adv = *(const float4*)(al + (size_t)wid * 16 + doff);
    int l5 = lane & 31, h2 = l5 >> 3, half = lane >> 5;

    float acc0 = 0.f, acc1 = 0.f, acc2 = 0.f, acc3 = 0.f;
    float dn0 = 0.f, dn1 = 0.f, dn2 = 0.f, dn3 = 0.f;

    for (int cb = b; cb < e; cb += 64) {
        int cnt = min(64, e - cb);
        int s = 0;
        float w0 = 0.f, w1 = 0.f, w2 = 0.f, w3 = 0.f;
        if (lane < cnt) {
            s = csr[cb + lane];
            float4 av = *(const float4*)(al + (size_t)s * 16);
            float a0 = av.x + adv.x; a0 = a0 > 0.f ? a0 : 0.2f * a0; w0 = __expf(a0);
            float a1 = av.y + adv.y; a1 = a1 > 0.f ? a1 : 0.2f * a1; w1 = __expf(a1);
            float a2 = av.z + adv.z; a2 = a2 > 0.f ? a2 : 0.2f * a2; w2 = __expf(a2);
            float a3 = av.w + adv.w; a3 = a3 > 0.f ? a3 : 0.2f * a3; w3 = __expf(a3);
        }
        dn0 += w0; dn1 += w1; dn2 += w2; dn3 += w3;
        sbuf[wv][lane] = s;
        float4 wq; wq.x = w0; wq.y = w1; wq.z = w2; wq.w = w3;
        *(float4*)&wbuf[wv][lane][0] = wq;
        #pragma unroll 4
        for (int j = 0; j < cnt; j += 2) {
            int jj = j + half;              // half 1 may read j==cnt (odd tail): w=0 there
            int sj = sbuf[wv][jj];
            float wj = wbuf[wv][jj][h2];
            u32 pk = xbv[(size_t)sj * 32 + l5];
            f32x2 c01 = __builtin_amdgcn_cvt_pk_f32_fp8(pk, false);
            f32x2 c23 = __builtin_amdgcn_cvt_pk_f32_fp8(pk, true);
            acc0 = fmaf(wj, c01.x, acc0);
            acc1 = fmaf(wj, c01.y, acc1);
            acc2 = fmaf(wj, c23.x, acc2);
            acc3 = fmaf(wj, c23.y, acc3);
        }
    }
    acc0 += __shfl_xor(acc0, 32);
    acc1 += __shfl_xor(acc1, 32);
    acc2 += __shfl_xor(acc2, 32);
    acc3 += __shfl_xor(acc3, 32);
    #pragma unroll
    for (int o = 32; o > 0; o >>= 1) {
        dn0 += __shfl_xor(dn0, o);
        dn1 += __shfl_xor(dn1, o);
        dn2 += __shfl_xor(dn2, o);
        dn3 += __shfl_xor(dn3, o);
    }
    float dh = (h2 == 0) ? dn0 : (h2 == 1) ? dn1 : (h2 == 2) ? dn2 : dn3;
    float inv = 1.f / (dh + 1e-16f);
    float r0 = acc0 * inv, r1 = acc1 * inv, r2 = acc2 * inv, r3 = acc3 * inv;
    r0 = r0 > 0.f ? r0 : __expf(r0) - 1.f;
    r1 = r1 > 0.f ? r1 : __expf(r1) - 1.f;
    r2 = r2 > 0.f ? r2 : __expf(r2) - 1.f;
    r3 = r3 > 0.f ? r3 : __expf(r3) - 1.f;
    if (half == 0) {
        uint2 st;
        st.x = (u32)f2bf(r0) | ((u32)f2bf(r1) << 16);
        st.y = (u32)f2bf(r2) | ((u32)f2bf(r3) << 16);
        *(uint2*)(out + (size_t)wid * 256 + 4 * l5) = st;
    }
}

// ---------------- layer-2 propagate ----------------
__global__ __launch_bounds__(256) void k_prop2(const int* __restrict__ ptr, const u16* __restrict__ csr,
                                               const float* __restrict__ al, int didx,
                                               const uint2* __restrict__ xbv,
                                               float* __restrict__ out, int n) {
    __shared__ int2 swb[4][64];
    int tid = threadIdx.x;
    int wv = tid >> 6, lane = tid & 63;
    int wid = (blockIdx.x * 256 + tid) >> 6;
    if (wid >= n) return;
    int b = ptr[wid], e = ptr[wid + 1];
    float ad = al[(size_t)wid * 4 + didx];
    int g = lane / 10;
    int cp = lane - g * 10;
    bool act = g < 6;

    float acc0 = 0.f, acc1 = 0.f, acc2 = 0.f, acc3 = 0.f;
    float den = 0.f;

    for (int cb = b; cb < e; cb += 64) {
        int cnt = min(64, e - cb);
        int s = 0; float w = 0.f;
        if (lane < cnt) {
            s = csr[cb + lane];
            float a = al[(size_t)s * 4] + ad;
            a = a > 0.f ? a : 0.2f * a;
            w = __expf(a);
        }
        den += w;
        swb[wv][lane] = make_int2(s, __float_as_int(w));
        #pragma unroll 2
        for (int j = 0; j < cnt; j += 6) {
            int jj = j + g;
            bool valid = act && (jj < cnt);
            int2 sw = swb[wv][valid ? jj : 0];
            float wj = valid ? __int_as_float(sw.y) : 0.f;
            uint2 pk = xbv[(size_t)sw.x * 10 + cp];
            acc0 = fmaf(wj, bl(pk.x), acc0);
            acc1 = fmaf(wj, bh(pk.x), acc1);
            acc2 = fmaf(wj, bl(pk.y), acc2);
            acc3 = fmaf(wj, bh(pk.y), acc3);
        }
    }
    float t0;
    t0 = acc0 + __shfl(acc0, (lane + 30) & 63); acc0 = t0 + __shfl(t0, (lane + 10) & 63) + __shfl(t0, (lane + 20) & 63);
    t0 = acc1 + __shfl(acc1, (lane + 30) & 63); acc1 = t0 + __shfl(t0, (lane + 10) & 63) + __shfl(t0, (lane + 20) & 63);
    t0 = acc2 + __shfl(acc2, (lane + 30) & 63); acc2 = t0 + __shfl(t0, (lane + 10) & 63) + __shfl(t0, (lane + 20) & 63);
    t0 = acc3 + __shfl(acc3, (lane + 30) & 63); acc3 = t0 + __shfl(t0, (lane + 10) & 63) + __shfl(t0, (lane + 20) & 63);
    #pragma unroll
    for (int o = 32; o > 0; o >>= 1) den += __shfl_xor(den, o);
    if (lane < 10) {
        float inv = 1.f / (den + 1e-16f);
        float4 st; st.x = acc0 * inv; st.y = acc1 * inv; st.z = acc2 * inv; st.w = acc3 * inv;
        *(float4*)(out + (size_t)wid * 80 + 4 * cp) = st;
    }
}

// ---------------- log_softmax ----------------
__global__ __launch_bounds__(256) void k_lsm(const float* __restrict__ h2, float* __restrict__ out, int n) {
    int wid = (blockIdx.x * blockDim.x + threadIdx.x) >> 6;
    int lane = threadIdx.x & 63;
    if (wid >= n) return;
    const float* row = h2 + (size_t)wid * 80;
    float v0 = row[lane];
    float v1 = (lane < 16) ? row[64 + lane] : -INFINITY;
    float m = fmaxf(v0, v1);
    for (int o = 32; o > 0; o >>= 1) m = fmaxf(m, __shfl_xor(m, o));
    float s = __expf(v0 - m) + ((lane < 16) ? __expf(v1 - m) : 0.f);
    for (int o = 32; o > 0; o >>= 1) s += __shfl_xor(s, o);
    float ls = m + logf(s);
    out[(size_t)wid * 80 + lane] = v0 - ls;
    if (lane < 16) out[(size_t)wid * 80 + 64 + lane] = v1 - ls;
}

// ---------------- launch ----------------

extern "C" void kernel_launch(void* const* d_in, const int* in_sizes, int n_in,
                              void* d_out, int out_size, void* d_ws, size_t ws_size,
                              hipStream_t stream) {
    const float* x       = (const float*)d_in[0];
    const int*   e1      = (const int*)d_in[1];
    const int*   e2      = (const int*)d_in[2];
    const float* W_src1  = (const float*)d_in[3];
    const float* W_dst1  = (const float*)d_in[4];
    const float* W_dst21 = (const float*)d_in[5];
    const float* a_src1  = (const float*)d_in[6];
    const float* a_dst1  = (const float*)d_in[7];
    const float* a_dst21 = (const float*)d_in[8];
    const float* W_src2  = (const float*)d_in[9];
    const float* W_dst2  = (const float*)d_in[10];
    const float* W_dst22 = (const float*)d_in[11];
    const float* a_src2  = (const float*)d_in[12];
    const float* a_dst2  = (const float*)d_in[13];
    const float* a_dst22 = (const float*)d_in[14];
    float* out = (float*)d_out;

    const int FIN = 500;
    int n  = in_sizes[0] / FIN;     // 50000
    int E1 = in_sizes[1] / 2;       // 300000
    int E2 = in_sizes[2] / 2;       // ~1.7M
    const int* src1 = e1, *dst1 = e1 + E1;
    const int* src2 = e2, *dst2 = e2 + E2;
    int nb = (n + 511) >> 9;        // 98

    char* w = (char*)d_ws;
    auto alloc = [&](size_t bytes) -> char* {
        char* p = w; w += (bytes + 255) & ~(size_t)255; return p;
    };
    u8*    xb1  = (u8*)alloc((size_t)n * 128);        // layer1 feats fp8 [n][128]
    float* alb1 = (float*)alloc((size_t)n * 16 * 4);  // [als(4)|ald1(4)|ald21(4)|pad]
    u16*   hbuf = (u16*)alloc((size_t)n * 256 * 2);   // elu(concat) hidden bf16 [n][256]
    u16*   xb2  = (u16*)alloc((size_t)n * 40 * 2);    // layer2 feats bf16 [n][40]
    float* alb2 = (float*)alloc((size_t)n * 4 * 4);   // [als|ald1|ald22|pad]
    float* h2   = (float*)alloc((size_t)n * 80 * 4);  // pre-logsoftmax fp32
    u16*   BF1  = (u16*)alloc((size_t)9 * 16 * 64 * 8 * 2);   // 147 KB fragment-major
    u16*   BF2  = (u16*)alloc((size_t)3 * 8 * 64 * 8 * 2);    // 24.6 KB
    int* ptr1 = (int*)alloc((size_t)(n + 1) * 4);
    u16* csr1 = (u16*)alloc((size_t)E1 * 2);
    int* ptr2 = (int*)alloc((size_t)(n + 1) * 4);
    u16* csr2 = (u16*)alloc((size_t)E2 * 2);
    int* bcnt1  = (int*)alloc(NB * 4);
    int* bcnt2  = (int*)alloc(NB * 4);
    int* bbase1 = (int*)alloc((NB + 1) * 4);
    int* bbase2 = (int*)alloc((NB + 1) * 4);
    int* bcur1  = (int*)alloc(NB * 4);
    int* bcur2  = (int*)alloc(NB * 4);
    // partition scratch aliases h2 (dead until k_prop2; stream-ordered)
    u32* part2 = (u32*)h2;
    u32* part1 = part2 + E2;

    // CSR build (bucket-first)
    hipMemsetAsync(bcnt1, 0, NB * 4, stream);
    hipMemsetAsync(bcnt2, 0, NB * 4, stream);
    k_bhist<<<(E1 + 2047) / 2048, 256, 0, stream>>>(dst1, E1, bcnt1);
    k_bhist<<<(E2 + 2047) / 2048, 256, 0, stream>>>(dst2, E2, bcnt2);
    k_bscan<<<1, NB, 0, stream>>>(bcnt1, bbase1, bcur1, ptr1 + n, nb);
    k_bscan<<<1, NB, 0, stream>>>(bcnt2, bbase2, bcur2, ptr2 + n, nb);
    k_part<<<(E1 + 2047) / 2048, 256, 0, stream>>>(src1, dst1, E1, bcur1, part1);
    k_part<<<(E2 + 2047) / 2048, 256, 0, stream>>>(src2, dst2, E2, bcur2, part2);
    k_dhs<<<nb, 256, 0, stream>>>(part1, bbase1, ptr1, csr1, n);
    k_dhs<<<nb, 256, 0, stream>>>(part2, bbase2, ptr2, csr2, n);

    // layer 1: fused MFMA GEMM (features fp8 + attention-logit projections fp32)
    k_build_BF1<<<(9 * 16 * 64 + 255) / 256, 256, 0, stream>>>(W_src1, W_dst1, W_dst21,
                                                               a_src1, a_dst1, a_dst21, BF1);
    int nw = (n + 15) / 16;
    int gw = (nw * 64 + 255) / 256;
    k_mgemm1<<<gw, 256, 0, stream>>>(x, (const uint4*)BF1, xb1, alb1, n);

    // layer 1 propagate (+ fused ELU), bf16 hidden out
    int pblocks = (n + 3) / 4;
    k_prop1<<<pblocks, 256, 0, stream>>>(ptr1, csr1, alb1, 4, (const u32*)xb1, hbuf + 0, n);
    k_prop1<<<pblocks, 256, 0, stream>>>(ptr2, csr2, alb1, 8, (const u32*)xb1, hbuf + 128, n);

    // layer 2: MFMA GEMM on bf16 hidden
    k_build_BF2<<<(3 * 8 * 64 + 255) / 256, 256, 0, stream>>>(W_src2, W_dst2, W_dst22,
                                                              a_src2, a_dst2, a_dst22, BF2);
    k_mgemm2<<<gw, 256, 0, stream>>>(hbuf, (const uint4*)BF2, xb2, alb2, n);

    // layer 2 propagate
    k_prop2<<<pblocks, 256, 0, stream>>>(ptr1, csr1, alb2, 1, (const uint2*)xb2, h2 + 0, n);
    k_prop2<<<pblocks, 256, 0, stream>>>(ptr2, csr2, alb2, 2, (const uint2*)xb2, h2 + 40, n);

    // log_softmax
    k_lsm<<<pblocks, 256, 0, stream>>>(h2, out, n);
}

// Round 14
// 292.494 us; speedup vs baseline: 1.0889x; 1.0889x over previous
//
#include <hip/hip_runtime.h>
#include <hip/hip_bf16.h>
#include <math.h>

typedef unsigned short u16;
typedef unsigned int u32;
typedef unsigned char u8;
typedef __attribute__((ext_vector_type(8))) short short8;
typedef __attribute__((ext_vector_type(4))) float f32x4;
typedef __attribute__((ext_vector_type(2))) float f32x2;

#define NB 128  // bucket slots (actual buckets = ceil(n/512) = 98 for n=50000)

static __device__ __forceinline__ u16 f2bf(float f) {
    u32 u = __float_as_uint(f);
    u32 r = (u + 0x7fffu + ((u >> 16) & 1u)) >> 16;
    return (u16)r;
}
static __device__ __forceinline__ float bl(u32 u) { return __uint_as_float(u << 16); }
static __device__ __forceinline__ float bh(u32 u) { return __uint_as_float(u & 0xffff0000u); }

// ---------------- CSR build (bucket-first, no per-node global atomics) --------

__global__ __launch_bounds__(256) void k_bhist(const int* __restrict__ dst, int E,
                                               int* __restrict__ bcnt) {
    __shared__ int lh[NB];
    int tid = threadIdx.x;
    int base = blockIdx.x * 2048;
    for (int i = tid; i < NB; i += 256) lh[i] = 0;
    __syncthreads();
    int cnt = min(2048, E - base);
    #pragma unroll
    for (int k = 0; k < 8; k++) {
        int i = tid + k * 256;
        if (i < cnt) atomicAdd(&lh[dst[base + i] >> 9], 1);
    }
    __syncthreads();
    for (int i = tid; i < NB; i += 256) {
        int c = lh[i];
        if (c) atomicAdd(&bcnt[i], c);
    }
}

__global__ void k_bscan(const int* __restrict__ bcnt, int* __restrict__ bbase,
                        int* __restrict__ bcur, int* __restrict__ ptrN, int nb) {
    __shared__ int sh[NB];
    int t = threadIdx.x;  // 128
    int v = (t < nb) ? bcnt[t] : 0;
    sh[t] = v;
    __syncthreads();
    for (int off = 1; off < NB; off <<= 1) {
        int val = sh[t];
        int add = (t >= off) ? sh[t - off] : 0;
        __syncthreads();
        sh[t] = val + add;
        __syncthreads();
    }
    int excl = sh[t] - v;
    if (t <= nb) bbase[t] = excl;
    if (t < nb) bcur[t] = excl;
    if (t == nb) *ptrN = excl;   // total = E
}

__global__ __launch_bounds__(256) void k_part(const int* __restrict__ src,
                                              const int* __restrict__ dst, int E,
                                              int* __restrict__ bcur,
                                              u32* __restrict__ part) {
    __shared__ int lh[NB];
    __shared__ int gb[NB];
    int tid = threadIdx.x;
    int base = blockIdx.x * 2048;
    for (int i = tid; i < NB; i += 256) lh[i] = 0;
    __syncthreads();
    int cnt = min(2048, E - base);
    int bkt[8], rank[8]; u32 pk[8];
    #pragma unroll
    for (int k = 0; k < 8; k++) {
        int i = tid + k * 256;
        if (i < cnt) {
            int s = src[base + i], d = dst[base + i];
            int b = d >> 9;
            bkt[k] = b;
            pk[k] = ((u32)(d & 511) << 16) | (u32)s;
            rank[k] = atomicAdd(&lh[b], 1);
        } else bkt[k] = -1;
    }
    __syncthreads();
    for (int i = tid; i < NB; i += 256) {
        int c = lh[i];
        gb[i] = c ? atomicAdd(&bcur[i], c) : 0;
    }
    __syncthreads();
    #pragma unroll
    for (int k = 0; k < 8; k++)
        if (bkt[k] >= 0) part[gb[bkt[k]] + rank[k]] = pk[k];
}

// per-bucket: hist of dstLow9 + in-LDS scan -> ptr; then scatter slice -> csr16
__global__ __launch_bounds__(256) void k_dhs(const u32* __restrict__ part,
                                             const int* __restrict__ bbase,
                                             int* __restrict__ ptrArr,
                                             u16* __restrict__ csr, int n) {
    __shared__ int hist[512];
    __shared__ int tsum[256];
    int b = blockIdx.x;
    int t = threadIdx.x;
    int lo = bbase[b], hi = bbase[b + 1];
    hist[t] = 0; hist[t + 256] = 0;
    __syncthreads();
    for (int i = lo + t; i < hi; i += 256)
        atomicAdd(&hist[(part[i] >> 16) & 511], 1);
    __syncthreads();
    int v0 = hist[2 * t], v1 = hist[2 * t + 1];
    tsum[t] = v0 + v1;
    __syncthreads();
    for (int off = 1; off < 256; off <<= 1) {
        int val = tsum[t];
        int add = (t >= off) ? tsum[t - off] : 0;
        __syncthreads();
        tsum[t] = val + add;
        __syncthreads();
    }
    int basep = lo + ((t == 0) ? 0 : tsum[t - 1]);
    int i0 = (b << 9) + 2 * t;
    if (i0 < n)     ptrArr[i0] = basep;
    if (i0 + 1 < n) ptrArr[i0 + 1] = basep + v0;
    __syncthreads();
    hist[2 * t] = basep;             // cursors
    hist[2 * t + 1] = basep + v0;
    __syncthreads();
    for (int i = lo + t; i < hi; i += 256) {
        u32 pk = part[i];
        int pos = atomicAdd(&hist[(pk >> 16) & 511], 1);
        csr[pos] = (u16)(pk & 0xffffu);
    }
}

// ---------------- weight prep (transposed bf16 B matrices) ----------------
__global__ void k_build_Bt1(const float* __restrict__ Ws, const float* __restrict__ Wd,
                            const float* __restrict__ Wd2, const float* __restrict__ as_,
                            const float* __restrict__ ad, const float* __restrict__ ad2,
                            u16* __restrict__ Bt) {
    int t = blockIdx.x * blockDim.x + threadIdx.x;
    if (t >= 144 * 512) return;
    int nn = t >> 9, k = t & 511;
    float v = 0.f;
    if (k < 500) {
        if (nn < 128) v = Ws[k * 128 + nn];
        else if (nn < 140) {
            int q = nn - 128; int h = q & 3;
            const float* W; const float* a;
            if (q < 4)      { W = Ws;  a = as_; }
            else if (q < 8) { W = Wd;  a = ad;  }
            else            { W = Wd2; a = ad2; }
            float s = 0.f;
            #pragma unroll 8
            for (int c = 0; c < 32; c++) s += W[k * 128 + h * 32 + c] * a[h * 32 + c];
            v = s;
        }
    }
    Bt[t] = f2bf(v);
}

__global__ void k_build_Bt2(const float* __restrict__ Ws, const float* __restrict__ Wd,
                            const float* __restrict__ Wd2, const float* __restrict__ as_,
                            const float* __restrict__ ad, const float* __restrict__ ad2,
                            u16* __restrict__ Bt) {
    int t = blockIdx.x * blockDim.x + threadIdx.x;
    if (t >= 48 * 256) return;
    int nn = t >> 8, k = t & 255;
    float v = 0.f;
    if (nn < 40) v = Ws[k * 40 + nn];
    else if (nn < 43) {
        const float* a = (nn == 40) ? as_ : (nn == 41) ? ad : ad2;
        const float* W = Ws;
        if (nn == 41) W = Wd; else if (nn == 42) W = Wd2;
        float s = 0.f;
        #pragma unroll 8
        for (int c = 0; c < 40; c++) s += W[k * 40 + c] * a[c];
        v = s;
    }
    Bt[t] = f2bf(v);
}

// ---------------- MFMA GEMM layer 1: B LDS-resident in 4 K-phases -------------
__global__ __launch_bounds__(256) void k_mgemm1(const float* __restrict__ A,
                                                const u16* __restrict__ Bt,
                                                u8* __restrict__ xb,
                                                float* __restrict__ alb, int M) {
    __shared__ __align__(16) u16 Bs[144][136];
    int tid = threadIdx.x;
    int wv = tid >> 6, lane = tid & 63;
    int l15 = lane & 15, k8 = lane >> 4;
    int wid = blockIdx.x * 4 + wv;
    int nw = (M + 15) >> 4;
    bool active = wid < nw;
    int rowBlk = wid * 16;
    int arow = rowBlk + l15;
    bool rowOK = active && (arow < M);
    const float* Ap0 = A + (size_t)arow * 500;

    f32x4 acc[9];
    #pragma unroll
    for (int t = 0; t < 9; t++) acc[t] = (f32x4){0.f, 0.f, 0.f, 0.f};

    for (int q = 0; q < 4; q++) {
        if (q) __syncthreads();
        for (int idx = tid; idx < 2304; idx += 256) {
            int row = idx >> 4, c = (idx & 15) * 8;
            *(uint4*)&Bs[row][c] = *(const uint4*)&Bt[row * 512 + q * 128 + c];
        }
        __syncthreads();
        #pragma unroll
        for (int ki = 0; ki < 4; ki++) {
            int kg = q * 128 + ki * 32 + k8 * 8;
            float v[8];
            if (rowOK && (kg + 8 <= 500)) {
                float4 p0 = *(const float4*)(Ap0 + kg);
                float4 p1 = *(const float4*)(Ap0 + kg + 4);
                v[0] = p0.x; v[1] = p0.y; v[2] = p0.z; v[3] = p0.w;
                v[4] = p1.x; v[5] = p1.y; v[6] = p1.z; v[7] = p1.w;
            } else {
                #pragma unroll
                for (int i = 0; i < 8; i++)
                    v[i] = (rowOK && kg + i < 500) ? Ap0[kg + i] : 0.f;
            }
            short8 af;
            ((u32*)&af)[0] = (u32)f2bf(v[0]) | ((u32)f2bf(v[1]) << 16);
            ((u32*)&af)[1] = (u32)f2bf(v[2]) | ((u32)f2bf(v[3]) << 16);
            ((u32*)&af)[2] = (u32)f2bf(v[4]) | ((u32)f2bf(v[5]) << 16);
            ((u32*)&af)[3] = (u32)f2bf(v[6]) | ((u32)f2bf(v[7]) << 16);
            int kl = ki * 32 + k8 * 8;
            #pragma unroll
            for (int t = 0; t < 9; t++) {
                short8 bf = *(const short8*)&Bs[t * 16 + l15][kl];
                acc[t] = __builtin_amdgcn_mfma_f32_16x16x32_bf16(af, bf, acc[t], 0, 0, 0);
            }
        }
    }
    if (active) {
        #pragma unroll
        for (int t = 0; t < 9; t++) {
            #pragma unroll
            for (int rr = 0; rr < 4; rr++) {
                int grow = rowBlk + k8 * 4 + rr;
                if (grow < M) {
                    if (t < 8) {
                        u32 p8 = __builtin_amdgcn_cvt_pk_fp8_f32(acc[t][rr], acc[t][rr], 0, false);
                        xb[(size_t)grow * 128 + t * 16 + l15] = (u8)(p8 & 0xffu);
                    } else if (l15 < 12) {
                        alb[(size_t)grow * 16 + l15] = acc[t][rr];
                    }
                }
            }
        }
    }
}

// ---------------- MFMA GEMM layer 2: whole B LDS-resident, 1 barrier ----------
__global__ __launch_bounds__(256) void k_mgemm2(const u16* __restrict__ A,
                                                const u16* __restrict__ Bt,
                                                u16* __restrict__ xb,
                                                float* __restrict__ alb, int M) {
    __shared__ __align__(16) u16 Bs[48][264];
    int tid = threadIdx.x;
    int wv = tid >> 6, lane = tid & 63;
    int l15 = lane & 15, k8 = lane >> 4;
    int wid = blockIdx.x * 4 + wv;
    int nw = (M + 15) >> 4;
    bool active = wid < nw;
    int rowBlk = wid * 16;
    int arow = rowBlk + l15;
    bool rowOK = active && (arow < M);
    const u16* Ap0 = A + (size_t)arow * 256;

    for (int idx = tid; idx < 1536; idx += 256) {
        int row = idx >> 5, c = (idx & 31) * 8;
        *(uint4*)&Bs[row][c] = *(const uint4*)&Bt[row * 256 + c];
    }
    __syncthreads();

    f32x4 acc[3];
    #pragma unroll
    for (int t = 0; t < 3; t++) acc[t] = (f32x4){0.f, 0.f, 0.f, 0.f};

    #pragma unroll
    for (int ki = 0; ki < 8; ki++) {
        int k0 = ki * 32 + k8 * 8;
        short8 af = {0, 0, 0, 0, 0, 0, 0, 0};
        if (rowOK) af = *(const short8*)(Ap0 + k0);
        #pragma unroll
        for (int t = 0; t < 3; t++) {
            short8 bf = *(const short8*)&Bs[t * 16 + l15][k0];
            acc[t] = __builtin_amdgcn_mfma_f32_16x16x32_bf16(af, bf, acc[t], 0, 0, 0);
        }
    }
    if (active) {
        #pragma unroll
        for (int t = 0; t < 3; t++) {
            #pragma unroll
            for (int rr = 0; rr < 4; rr++) {
                int grow = rowBlk + k8 * 4 + rr;
                if (grow < M) {
                    int col = t * 16 + l15;
                    if (col < 40) xb[(size_t)grow * 40 + col] = f2bf(acc[t][rr]);
                    else if (col < 43) alb[(size_t)grow * 4 + (col - 40)] = acc[t][rr];
                }
            }
        }
    }
}

// ---------------- layer-1 propagate: 4 edges/iter, 16 lanes x 8ch each --------
// quarter q = lane>>4 handles edge j+q; lane l4 = lane&15 covers channels
// l4*8..l4*8+7 (head h = l4>>2). Gather = uint2 (8B) -> 4 x 128B segments/iter.
__global__ __launch_bounds__(256) void k_prop1(const int* __restrict__ ptr, const u16* __restrict__ csr,
                                               const float* __restrict__ al, int doff,
                                               const uint2* __restrict__ xb2v,
                                               u16* __restrict__ out, int n) {
    __shared__ int sbuf[4][64];
    __shared__ __align__(16) float wbuf[4][64][4];
    int tid = threadIdx.x;
    int wv = tid >> 6, lane = tid & 63;
    int wid = (blockIdx.x * 256 + tid) >> 6;
    if (wid >= n) return;
    int b = ptr[wid], e = ptr[wid + 1];
    float4 adv = *(const float4*)(al + (size_t)wid * 16 + doff);
    int l4 = lane & 15, q = lane >> 4;
    int h = l4 >> 2;

    float acc0 = 0.f, acc1 = 0.f, acc2 = 0.f, acc3 = 0.f;
    float acc4 = 0.f, acc5 = 0.f, acc6 = 0.f, acc7 = 0.f;
    float dn0 = 0.f, dn1 = 0.f, dn2 = 0.f, dn3 = 0.f;

    for (int cb = b; cb < e; cb += 64) {
        int cnt = min(64, e - cb);
        int s = 0;
        float w0 = 0.f, w1 = 0.f, w2 = 0.f, w3 = 0.f;
        if (lane < cnt) {
            s = csr[cb + lane];
            float4 av = *(const float4*)(al + (size_t)s * 16);
            float a0 = av.x + adv.x; a0 = a0 > 0.f ? a0 : 0.2f * a0; w0 = __expf(a0);
            float a1 = av.y + adv.y; a1 = a1 > 0.f ? a1 : 0.2f * a1; w1 = __expf(a1);
            float a2 = av.z + adv.z; a2 = a2 > 0.f ? a2 : 0.2f * a2; w2 = __expf(a2);
            float a3 = av.w + adv.w; a3 = a3 > 0.f ? a3 : 0.2f * a3; w3 = __expf(a3);
        }
        dn0 += w0; dn1 += w1; dn2 += w2; dn3 += w3;
        sbuf[wv][lane] = s;
        float4 wq4; wq4.x = w0; wq4.y = w1; wq4.z = w2; wq4.w = w3;
        *(float4*)&wbuf[wv][lane][0] = wq4;
        // lanes >= cnt wrote s=0,w=0, so jq in [cnt,64) contributes 0.
        #pragma unroll 2
        for (int j = 0; j < cnt; j += 4) {
            int jq = j + q;
            int sj = sbuf[wv][jq];
            float wj = wbuf[wv][jq][h];
            uint2 pk = xb2v[(size_t)sj * 16 + l4];
            f32x2 c01 = __builtin_amdgcn_cvt_pk_f32_fp8(pk.x, false);
            f32x2 c23 = __builtin_amdgcn_cvt_pk_f32_fp8(pk.x, true);
            f32x2 c45 = __builtin_amdgcn_cvt_pk_f32_fp8(pk.y, false);
            f32x2 c67 = __builtin_amdgcn_cvt_pk_f32_fp8(pk.y, true);
            acc0 = fmaf(wj, c01.x, acc0);
            acc1 = fmaf(wj, c01.y, acc1);
            acc2 = fmaf(wj, c23.x, acc2);
            acc3 = fmaf(wj, c23.y, acc3);
            acc4 = fmaf(wj, c45.x, acc4);
            acc5 = fmaf(wj, c45.y, acc5);
            acc6 = fmaf(wj, c67.x, acc6);
            acc7 = fmaf(wj, c67.y, acc7);
        }
    }
    // reduce across quarters (lanes l, l+16, l+32, l+48)
    acc0 += __shfl_xor(acc0, 16); acc0 += __shfl_xor(acc0, 32);
    acc1 += __shfl_xor(acc1, 16); acc1 += __shfl_xor(acc1, 32);
    acc2 += __shfl_xor(acc2, 16); acc2 += __shfl_xor(acc2, 32);
    acc3 += __shfl_xor(acc3, 16); acc3 += __shfl_xor(acc3, 32);
    acc4 += __shfl_xor(acc4, 16); acc4 += __shfl_xor(acc4, 32);
    acc5 += __shfl_xor(acc5, 16); acc5 += __shfl_xor(acc5, 32);
    acc6 += __shfl_xor(acc6, 16); acc6 += __shfl_xor(acc6, 32);
    acc7 += __shfl_xor(acc7, 16); acc7 += __shfl_xor(acc7, 32);
    #pragma unroll
    for (int o = 32; o > 0; o >>= 1) {
        dn0 += __shfl_xor(dn0, o);
        dn1 += __shfl_xor(dn1, o);
        dn2 += __shfl_xor(dn2, o);
        dn3 += __shfl_xor(dn3, o);
    }
    if (lane < 16) {
        float dh = (h == 0) ? dn0 : (h == 1) ? dn1 : (h == 2) ? dn2 : dn3;
        float inv = 1.f / (dh + 1e-16f);
        float r0 = acc0 * inv, r1 = acc1 * inv, r2 = acc2 * inv, r3 = acc3 * inv;
        float r4 = acc4 * inv, r5 = acc5 * inv, r6 = acc6 * inv, r7 = acc7 * inv;
        r0 = r0 > 0.f ? r0 : __expf(r0) - 1.f;
        r1 = r1 > 0.f ? r1 : __expf(r1) - 1.f;
        r2 = r2 > 0.f ? r2 : __expf(r2) - 1.f;
        r3 = r3 > 0.f ? r3 : __expf(r3) - 1.f;
        r4 = r4 > 0.f ? r4 : __expf(r4) - 1.f;
        r5 = r5 > 0.f ? r5 : __expf(r5) - 1.f;
        r6 = r6 > 0.f ? r6 : __expf(r6) - 1.f;
        r7 = r7 > 0.f ? r7 : __expf(r7) - 1.f;
        uint4 st;
        st.x = (u32)f2bf(r0) | ((u32)f2bf(r1) << 16);
        st.y = (u32)f2bf(r2) | ((u32)f2bf(r3) << 16);
        st.z = (u32)f2bf(r4) | ((u32)f2bf(r5) << 16);
        st.w = (u32)f2bf(r6) | ((u32)f2bf(r7) << 16);
        *(uint4*)(out + (size_t)wid * 256 + l4 * 8) = st;
    }
}

// ---------------- layer-2 propagate ----------------
__global__ __launch_bounds__(256) void k_prop2(const int* __restrict__ ptr, const u16* __restrict__ csr,
                                               const float* __restrict__ al, int didx,
                                               const uint2* __restrict__ xbv,
                                               float* __restrict__ out, int n) {
    __shared__ int2 swb[4][64];
    int tid = threadIdx.x;
    int wv = tid >> 6, lane = tid & 63;
    int wid = (blockIdx.x * 256 + tid) >> 6;
    if (wid >= n) return;
    int b = ptr[wid], e = ptr[wid + 1];
    float ad = al[(size_t)wid * 4 + didx];
    int g = lane / 10;
    int cp = lane - g * 10;
    bool act = g < 6;

    float acc0 = 0.f, acc1 = 0.f, acc2 = 0.f, acc3 = 0.f;
    float den = 0.f;

    for (int cb = b; cb < e; cb += 64) {
        int cnt = min(64, e - cb);
        int s = 0; float w = 0.f;
        if (lane < cnt) {
            s = csr[cb + lane];
            float a = al[(size_t)s * 4] + ad;
            a = a > 0.f ? a : 0.2f * a;
            w = __expf(a);
        }
        den += w;
        swb[wv][lane] = make_int2(s, __float_as_int(w));
        #pragma unroll 2
        for (int j = 0; j < cnt; j += 6) {
            int jj = j + g;
            bool valid = act && (jj < cnt);
            int2 sw = swb[wv][valid ? jj : 0];
            float wj = valid ? __int_as_float(sw.y) : 0.f;
            uint2 pk = xbv[(size_t)sw.x * 10 + cp];
            acc0 = fmaf(wj, bl(pk.x), acc0);
            acc1 = fmaf(wj, bh(pk.x), acc1);
            acc2 = fmaf(wj, bl(pk.y), acc2);
            acc3 = fmaf(wj, bh(pk.y), acc3);
        }
    }
    float t0;
    t0 = acc0 + __shfl(acc0, (lane + 30) & 63); acc0 = t0 + __shfl(t0, (lane + 10) & 63) + __shfl(t0, (lane + 20) & 63);
    t0 = acc1 + __shfl(acc1, (lane + 30) & 63); acc1 = t0 + __shfl(t0, (lane + 10) & 63) + __shfl(t0, (lane + 20) & 63);
    t0 = acc2 + __shfl(acc2, (lane + 30) & 63); acc2 = t0 + __shfl(t0, (lane + 10) & 63) + __shfl(t0, (lane + 20) & 63);
    t0 = acc3 + __shfl(acc3, (lane + 30) & 63); acc3 = t0 + __shfl(t0, (lane + 10) & 63) + __shfl(t0, (lane + 20) & 63);
    #pragma unroll
    for (int o = 32; o > 0; o >>= 1) den += __shfl_xor(den, o);
    if (lane < 10) {
        float inv = 1.f / (den + 1e-16f);
        float4 st; st.x = acc0 * inv; st.y = acc1 * inv; st.z = acc2 * inv; st.w = acc3 * inv;
        *(float4*)(out + (size_t)wid * 80 + 4 * cp) = st;
    }
}

// ---------------- log_softmax ----------------
__global__ __launch_bounds__(256) void k_lsm(const float* __restrict__ h2, float* __restrict__ out, int n) {
    int wid = (blockIdx.x * blockDim.x + threadIdx.x) >> 6;
    int lane = threadIdx.x & 63;
    if (wid >= n) return;
    const float* row = h2 + (size_t)wid * 80;
    float v0 = row[lane];
    float v1 = (lane < 16) ? row[64 + lane] : -INFINITY;
    float m = fmaxf(v0, v1);
    for (int o = 32; o > 0; o >>= 1) m = fmaxf(m, __shfl_xor(m, o));
    float s = __expf(v0 - m) + ((lane < 16) ? __expf(v1 - m) : 0.f);
    for (int o = 32; o > 0; o >>= 1) s += __shfl_xor(s, o);
    float ls = m + logf(s);
    out[(size_t)wid * 80 + lane] = v0 - ls;
    if (lane < 16) out[(size_t)wid * 80 + 64 + lane] = v1 - ls;
}

// ---------------- launch ----------------

extern "C" void kernel_launch(void* const* d_in, const int* in_sizes, int n_in,
                              void* d_out, int out_size, void* d_ws, size_t ws_size,
                              hipStream_t stream) {
    const float* x       = (const float*)d_in[0];
    const int*   e1      = (const int*)d_in[1];
    const int*   e2      = (const int*)d_in[2];
    const float* W_src1  = (const float*)d_in[3];
    const float* W_dst1  = (const float*)d_in[4];
    const float* W_dst21 = (const float*)d_in[5];
    const float* a_src1  = (const float*)d_in[6];
    const float* a_dst1  = (const float*)d_in[7];
    const float* a_dst21 = (const float*)d_in[8];
    const float* W_src2  = (const float*)d_in[9];
    const float* W_dst2  = (const float*)d_in[10];
    const float* W_dst22 = (const float*)d_in[11];
    const float* a_src2  = (const float*)d_in[12];
    const float* a_dst2  = (const float*)d_in[13];
    const float* a_dst22 = (const float*)d_in[14];
    float* out = (float*)d_out;

    const int FIN = 500;
    int n  = in_sizes[0] / FIN;     // 50000
    int E1 = in_sizes[1] / 2;       // 300000
    int E2 = in_sizes[2] / 2;       // ~1.7M
    const int* src1 = e1, *dst1 = e1 + E1;
    const int* src2 = e2, *dst2 = e2 + E2;
    int nb = (n + 511) >> 9;        // 98

    char* w = (char*)d_ws;
    auto alloc = [&](size_t bytes) -> char* {
        char* p = w; w += (bytes + 255) & ~(size_t)255; return p;
    };
    u8*    xb1  = (u8*)alloc((size_t)n * 128);        // layer1 feats fp8 [n][128]
    float* alb1 = (float*)alloc((size_t)n * 16 * 4);  // [als(4)|ald1(4)|ald21(4)|pad]
    u16*   hbuf = (u16*)alloc((size_t)n * 256 * 2);   // elu(concat) hidden bf16 [n][256]
    u16*   xb2  = (u16*)alloc((size_t)n * 40 * 2);    // layer2 feats bf16 [n][40]
    float* alb2 = (float*)alloc((size_t)n * 4 * 4);   // [als|ald1|ald22|pad]
    float* h2   = (float*)alloc((size_t)n * 80 * 4);  // pre-logsoftmax fp32
    u16*   Bt1  = (u16*)alloc(144 * 512 * 2);
    u16*   Bt2  = (u16*)alloc(48 * 256 * 2);
    int* ptr1 = (int*)alloc((size_t)(n + 1) * 4);
    u16* csr1 = (u16*)alloc((size_t)E1 * 2);
    int* ptr2 = (int*)alloc((size_t)(n + 1) * 4);
    u16* csr2 = (u16*)alloc((size_t)E2 * 2);
    int* bcnt1  = (int*)alloc(NB * 4);
    int* bcnt2  = (int*)alloc(NB * 4);
    int* bbase1 = (int*)alloc((NB + 1) * 4);
    int* bbase2 = (int*)alloc((NB + 1) * 4);
    int* bcur1  = (int*)alloc(NB * 4);
    int* bcur2  = (int*)alloc(NB * 4);
    // partition scratch aliases h2 (dead until k_prop2; stream-ordered)
    u32* part2 = (u32*)h2;
    u32* part1 = part2 + E2;

    // CSR build (bucket-first)
    hipMemsetAsync(bcnt1, 0, NB * 4, stream);
    hipMemsetAsync(bcnt2, 0, NB * 4, stream);
    k_bhist<<<(E1 + 2047) / 2048, 256, 0, stream>>>(dst1, E1, bcnt1);
    k_bhist<<<(E2 + 2047) / 2048, 256, 0, stream>>>(dst2, E2, bcnt2);
    k_bscan<<<1, NB, 0, stream>>>(bcnt1, bbase1, bcur1, ptr1 + n, nb);
    k_bscan<<<1, NB, 0, stream>>>(bcnt2, bbase2, bcur2, ptr2 + n, nb);
    k_part<<<(E1 + 2047) / 2048, 256, 0, stream>>>(src1, dst1, E1, bcur1, part1);
    k_part<<<(E2 + 2047) / 2048, 256, 0, stream>>>(src2, dst2, E2, bcur2, part2);
    k_dhs<<<nb, 256, 0, stream>>>(part1, bbase1, ptr1, csr1, n);
    k_dhs<<<nb, 256, 0, stream>>>(part2, bbase2, ptr2, csr2, n);

    // layer 1: fused MFMA GEMM (features fp8 + attention-logit projections fp32)
    k_build_Bt1<<<(144 * 512 + 255) / 256, 256, 0, stream>>>(W_src1, W_dst1, W_dst21,
                                                             a_src1, a_dst1, a_dst21, Bt1);
    int nw = (n + 15) / 16;
    k_mgemm1<<<(nw + 3) / 4, 256, 0, stream>>>(x, Bt1, xb1, alb1, n);

    // layer 1 propagate (+ fused ELU), bf16 hidden out
    int pblocks = (n + 3) / 4;
    k_prop1<<<pblocks, 256, 0, stream>>>(ptr1, csr1, alb1, 4, (const uint2*)xb1, hbuf + 0, n);
    k_prop1<<<pblocks, 256, 0, stream>>>(ptr2, csr2, alb1, 8, (const uint2*)xb1, hbuf + 128, n);

    // layer 2: MFMA GEMM on bf16 hidden
    k_build_Bt2<<<(48 * 256 + 255) / 256, 256, 0, stream>>>(W_src2, W_dst2, W_dst22,
                                                            a_src2, a_dst2, a_dst22, Bt2);
    k_mgemm2<<<(nw + 3) / 4, 256, 0, stream>>>(hbuf, Bt2, xb2, alb2, n);

    // layer 2 propagate
    k_prop2<<<pblocks, 256, 0, stream>>>(ptr1, csr1, alb2, 1, (const uint2*)xb2, h2 + 0, n);
    k_prop2<<<pblocks, 256, 0, stream>>>(ptr2, csr2, alb2, 2, (const uint2*)xb2, h2 + 40, n);

    // log_softmax
    k_lsm<<<pblocks, 256, 0, stream>>>(h2, out, n);
}

// Round 15
// 276.204 us; speedup vs baseline: 1.1531x; 1.0590x over previous
//
#include <hip/hip_runtime.h>
#include <hip/hip_bf16.h>
#include <math.h>

typedef unsigned short u16;
typedef unsigned int u32;
typedef unsigned char u8;
typedef __attribute__((ext_vector_type(8))) short short8;
typedef __attribute__((ext_vector_type(4))) float f32x4;
typedef __attribute__((ext_vector_type(2))) float f32x2;

#define NB 128  // bucket slots (actual buckets = ceil(n/512) = 98 for n=50000)

static __device__ __forceinline__ u16 f2bf(float f) {
    u32 u = __float_as_uint(f);
    u32 r = (u + 0x7fffu + ((u >> 16) & 1u)) >> 16;
    return (u16)r;
}
static __device__ __forceinline__ float bl(u32 u) { return __uint_as_float(u << 16); }
static __device__ __forceinline__ float bh(u32 u) { return __uint_as_float(u & 0xffff0000u); }

// ---------------- CSR build (fused pairs, bucket-first) ----------------

__global__ __launch_bounds__(256) void k_bhist2(const int* __restrict__ dst1, int E1,
                                                int* __restrict__ bcnt1,
                                                const int* __restrict__ dst2, int E2,
                                                int* __restrict__ bcnt2, int nblk1) {
    __shared__ int lh[NB];
    const int* dst; int E; int* bcnt; int bb;
    if (blockIdx.x < nblk1) { dst = dst1; E = E1; bcnt = bcnt1; bb = blockIdx.x; }
    else                    { dst = dst2; E = E2; bcnt = bcnt2; bb = blockIdx.x - nblk1; }
    int tid = threadIdx.x;
    int base = bb * 2048;
    for (int i = tid; i < NB; i += 256) lh[i] = 0;
    __syncthreads();
    int cnt = min(2048, E - base);
    #pragma unroll
    for (int k = 0; k < 8; k++) {
        int i = tid + k * 256;
        if (i < cnt) atomicAdd(&lh[dst[base + i] >> 9], 1);
    }
    __syncthreads();
    for (int i = tid; i < NB; i += 256) {
        int c = lh[i];
        if (c) atomicAdd(&bcnt[i], c);
    }
}

__global__ void k_bscan2(const int* __restrict__ bcnt1, int* __restrict__ bbase1,
                         int* __restrict__ bcur1, int* __restrict__ ptrN1,
                         const int* __restrict__ bcnt2, int* __restrict__ bbase2,
                         int* __restrict__ bcur2, int* __restrict__ ptrN2, int nb) {
    __shared__ int sh[NB];
    const int* bcnt = blockIdx.x ? bcnt2 : bcnt1;
    int* bbase = blockIdx.x ? bbase2 : bbase1;
    int* bcur  = blockIdx.x ? bcur2  : bcur1;
    int* ptrN  = blockIdx.x ? ptrN2  : ptrN1;
    int t = threadIdx.x;  // 128
    int v = (t < nb) ? bcnt[t] : 0;
    sh[t] = v;
    __syncthreads();
    for (int off = 1; off < NB; off <<= 1) {
        int val = sh[t];
        int add = (t >= off) ? sh[t - off] : 0;
        __syncthreads();
        sh[t] = val + add;
        __syncthreads();
    }
    int excl = sh[t] - v;
    if (t <= nb) bbase[t] = excl;
    if (t < nb) bcur[t] = excl;
    if (t == nb) *ptrN = excl;   // total = E
}

__global__ __launch_bounds__(256) void k_part2(const int* __restrict__ src1,
                                               const int* __restrict__ dst1, int E1,
                                               int* __restrict__ bcur1, u32* __restrict__ part1,
                                               const int* __restrict__ src2,
                                               const int* __restrict__ dst2, int E2,
                                               int* __restrict__ bcur2, u32* __restrict__ part2,
                                               int nblk1) {
    __shared__ int lh[NB];
    __shared__ int gb[NB];
    const int* src; const int* dst; int E; int* bcur; u32* part; int bb;
    if (blockIdx.x < nblk1) { src = src1; dst = dst1; E = E1; bcur = bcur1; part = part1; bb = blockIdx.x; }
    else                    { src = src2; dst = dst2; E = E2; bcur = bcur2; part = part2; bb = blockIdx.x - nblk1; }
    int tid = threadIdx.x;
    int base = bb * 2048;
    for (int i = tid; i < NB; i += 256) lh[i] = 0;
    __syncthreads();
    int cnt = min(2048, E - base);
    int bkt[8], rank[8]; u32 pk[8];
    #pragma unroll
    for (int k = 0; k < 8; k++) {
        int i = tid + k * 256;
        if (i < cnt) {
            int s = src[base + i], d = dst[base + i];
            int b = d >> 9;
            bkt[k] = b;
            pk[k] = ((u32)(d & 511) << 16) | (u32)s;
            rank[k] = atomicAdd(&lh[b], 1);
        } else bkt[k] = -1;
    }
    __syncthreads();
    for (int i = tid; i < NB; i += 256) {
        int c = lh[i];
        gb[i] = c ? atomicAdd(&bcur[i], c) : 0;
    }
    __syncthreads();
    #pragma unroll
    for (int k = 0; k < 8; k++)
        if (bkt[k] >= 0) part[gb[bkt[k]] + rank[k]] = pk[k];
}

// per-bucket: hist of dstLow9 + in-LDS scan -> ptr; then scatter slice -> csr16
__global__ __launch_bounds__(256) void k_dhs2(const u32* __restrict__ part1,
                                              const int* __restrict__ bbase1,
                                              int* __restrict__ ptrA1, u16* __restrict__ csr1,
                                              const u32* __restrict__ part2,
                                              const int* __restrict__ bbase2,
                                              int* __restrict__ ptrA2, u16* __restrict__ csr2,
                                              int n, int nbk) {
    __shared__ int hist[512];
    __shared__ int tsum[256];
    int b = blockIdx.x;
    const u32* part; const int* bbase; int* ptrArr; u16* csr;
    if (b < nbk) { part = part1; bbase = bbase1; ptrArr = ptrA1; csr = csr1; }
    else         { b -= nbk; part = part2; bbase = bbase2; ptrArr = ptrA2; csr = csr2; }
    int t = threadIdx.x;
    int lo = bbase[b], hi = bbase[b + 1];
    hist[t] = 0; hist[t + 256] = 0;
    __syncthreads();
    for (int i = lo + t; i < hi; i += 256)
        atomicAdd(&hist[(part[i] >> 16) & 511], 1);
    __syncthreads();
    int v0 = hist[2 * t], v1 = hist[2 * t + 1];
    tsum[t] = v0 + v1;
    __syncthreads();
    for (int off = 1; off < 256; off <<= 1) {
        int val = tsum[t];
        int add = (t >= off) ? tsum[t - off] : 0;
        __syncthreads();
        tsum[t] = val + add;
        __syncthreads();
    }
    int basep = lo + ((t == 0) ? 0 : tsum[t - 1]);
    int i0 = (b << 9) + 2 * t;
    if (i0 < n)     ptrArr[i0] = basep;
    if (i0 + 1 < n) ptrArr[i0 + 1] = basep + v0;
    __syncthreads();
    hist[2 * t] = basep;             // cursors
    hist[2 * t + 1] = basep + v0;
    __syncthreads();
    for (int i = lo + t; i < hi; i += 256) {
        u32 pk = part[i];
        int pos = atomicAdd(&hist[(pk >> 16) & 511], 1);
        csr[pos] = (u16)(pk & 0xffffu);
    }
}

// ---------------- weight prep (both transposed bf16 B matrices, one kernel) ---
__global__ void k_build2(const float* __restrict__ Ws1, const float* __restrict__ Wd1,
                         const float* __restrict__ Wd21, const float* __restrict__ as1,
                         const float* __restrict__ ad1, const float* __restrict__ ad21,
                         const float* __restrict__ Ws2, const float* __restrict__ Wd2,
                         const float* __restrict__ Wd22, const float* __restrict__ as2,
                         const float* __restrict__ ad2, const float* __restrict__ ad22,
                         u16* __restrict__ Bt1, u16* __restrict__ Bt2) {
    int t = blockIdx.x * blockDim.x + threadIdx.x;
    if (t < 144 * 512) {
        int nn = t >> 9, k = t & 511;
        float v = 0.f;
        if (k < 500) {
            if (nn < 128) v = Ws1[k * 128 + nn];
            else if (nn < 140) {
                int q = nn - 128; int h = q & 3;
                const float* W; const float* a;
                if (q < 4)      { W = Ws1;  a = as1; }
                else if (q < 8) { W = Wd1;  a = ad1;  }
                else            { W = Wd21; a = ad21; }
                float s = 0.f;
                #pragma unroll 8
                for (int c = 0; c < 32; c++) s += W[k * 128 + h * 32 + c] * a[h * 32 + c];
                v = s;
            }
        }
        Bt1[t] = f2bf(v);
    } else {
        t -= 144 * 512;
        if (t >= 48 * 256) return;
        int nn = t >> 8, k = t & 255;
        float v = 0.f;
        if (nn < 40) v = Ws2[k * 40 + nn];
        else if (nn < 43) {
            const float* a = (nn == 40) ? as2 : (nn == 41) ? ad2 : ad22;
            const float* W = Ws2;
            if (nn == 41) W = Wd2; else if (nn == 42) W = Wd22;
            float s = 0.f;
            #pragma unroll 8
            for (int c = 0; c < 40; c++) s += W[k * 40 + c] * a[c];
            v = s;
        }
        Bt2[t] = f2bf(v);
    }
}

// ---------------- MFMA GEMM layer 1: fragment-split, 2 waves per 16-row tile --
// gwid = 2*tile + halfw; halfw 0 computes t=0..4, halfw 1 computes t=5..8 (+alb).
// A read twice (L3-resident); B LDS phase-staged; 6250 waves -> ~50% occupancy.
__global__ __launch_bounds__(256) void k_mgemm1(const float* __restrict__ A,
                                                const u16* __restrict__ Bt,
                                                u8* __restrict__ xb,
                                                float* __restrict__ alb, int M) {
    __shared__ __align__(16) u16 Bs[144][136];
    int tid = threadIdx.x;
    int wv = tid >> 6, lane = tid & 63;
    int l15 = lane & 15, k8 = lane >> 4;
    int gwid = blockIdx.x * 4 + wv;
    int nw = (M + 15) >> 4;
    int tile = gwid >> 1;
    int halfw = gwid & 1;
    bool active = tile < nw;
    int rowBlk = tile * 16;
    int arow = rowBlk + l15;
    bool rowOK = active && (arow < M);
    const float* Ap0 = A + (size_t)arow * 500;
    int t0 = halfw ? 5 : 0;
    int tcnt = halfw ? 4 : 5;

    f32x4 acc[5];
    #pragma unroll
    for (int i = 0; i < 5; i++) acc[i] = (f32x4){0.f, 0.f, 0.f, 0.f};

    for (int q = 0; q < 4; q++) {
        if (q) __syncthreads();
        for (int idx = tid; idx < 2304; idx += 256) {
            int row = idx >> 4, c = (idx & 15) * 8;
            *(uint4*)&Bs[row][c] = *(const uint4*)&Bt[row * 512 + q * 128 + c];
        }
        __syncthreads();
        #pragma unroll
        for (int ki = 0; ki < 4; ki++) {
            int kg = q * 128 + ki * 32 + k8 * 8;
            float v[8];
            if (rowOK && (kg + 8 <= 500)) {
                float4 p0 = *(const float4*)(Ap0 + kg);
                float4 p1 = *(const float4*)(Ap0 + kg + 4);
                v[0] = p0.x; v[1] = p0.y; v[2] = p0.z; v[3] = p0.w;
                v[4] = p1.x; v[5] = p1.y; v[6] = p1.z; v[7] = p1.w;
            } else {
                #pragma unroll
                for (int i = 0; i < 8; i++)
                    v[i] = (rowOK && kg + i < 500) ? Ap0[kg + i] : 0.f;
            }
            short8 af;
            ((u32*)&af)[0] = (u32)f2bf(v[0]) | ((u32)f2bf(v[1]) << 16);
            ((u32*)&af)[1] = (u32)f2bf(v[2]) | ((u32)f2bf(v[3]) << 16);
            ((u32*)&af)[2] = (u32)f2bf(v[4]) | ((u32)f2bf(v[5]) << 16);
            ((u32*)&af)[3] = (u32)f2bf(v[6]) | ((u32)f2bf(v[7]) << 16);
            int kl = ki * 32 + k8 * 8;
            #pragma unroll
            for (int i = 0; i < 5; i++) {
                if (i < tcnt) {
                    short8 bf = *(const short8*)&Bs[(t0 + i) * 16 + l15][kl];
                    acc[i] = __builtin_amdgcn_mfma_f32_16x16x32_bf16(af, bf, acc[i], 0, 0, 0);
                }
            }
        }
    }
    if (active) {
        #pragma unroll
        for (int i = 0; i < 5; i++) {
            if (i < tcnt) {
                int t = t0 + i;
                #pragma unroll
                for (int rr = 0; rr < 4; rr++) {
                    int grow = rowBlk + k8 * 4 + rr;
                    if (grow < M) {
                        if (t < 8) {
                            u32 p8 = __builtin_amdgcn_cvt_pk_fp8_f32(acc[i][rr], acc[i][rr], 0, false);
                            xb[(size_t)grow * 128 + t * 16 + l15] = (u8)(p8 & 0xffu);
                        } else if (l15 < 12) {
                            alb[(size_t)grow * 16 + l15] = acc[i][rr];
                        }
                    }
                }
            }
        }
    }
}

// ---------------- MFMA GEMM layer 2: whole B LDS-resident, 1 barrier ----------
__global__ __launch_bounds__(256) void k_mgemm2(const u16* __restrict__ A,
                                                const u16* __restrict__ Bt,
                                                u16* __restrict__ xb,
                                                float* __restrict__ alb, int M) {
    __shared__ __align__(16) u16 Bs[48][264];
    int tid = threadIdx.x;
    int wv = tid >> 6, lane = tid & 63;
    int l15 = lane & 15, k8 = lane >> 4;
    int wid = blockIdx.x * 4 + wv;
    int nw = (M + 15) >> 4;
    bool active = wid < nw;
    int rowBlk = wid * 16;
    int arow = rowBlk + l15;
    bool rowOK = active && (arow < M);
    const u16* Ap0 = A + (size_t)arow * 256;

    for (int idx = tid; idx < 1536; idx += 256) {
        int row = idx >> 5, c = (idx & 31) * 8;
        *(uint4*)&Bs[row][c] = *(const uint4*)&Bt[row * 256 + c];
    }
    __syncthreads();

    f32x4 acc[3];
    #pragma unroll
    for (int t = 0; t < 3; t++) acc[t] = (f32x4){0.f, 0.f, 0.f, 0.f};

    #pragma unroll
    for (int ki = 0; ki < 8; ki++) {
        int k0 = ki * 32 + k8 * 8;
        short8 af = {0, 0, 0, 0, 0, 0, 0, 0};
        if (rowOK) af = *(const short8*)(Ap0 + k0);
        #pragma unroll
        for (int t = 0; t < 3; t++) {
            short8 bf = *(const short8*)&Bs[t * 16 + l15][k0];
            acc[t] = __builtin_amdgcn_mfma_f32_16x16x32_bf16(af, bf, acc[t], 0, 0, 0);
        }
    }
    if (active) {
        #pragma unroll
        for (int t = 0; t < 3; t++) {
            #pragma unroll
            for (int rr = 0; rr < 4; rr++) {
                int grow = rowBlk + k8 * 4 + rr;
                if (grow < M) {
                    int col = t * 16 + l15;
                    if (col < 40) xb[(size_t)grow * 40 + col] = f2bf(acc[t][rr]);
                    else if (col < 43) alb[(size_t)grow * 4 + (col - 40)] = acc[t][rr];
                }
            }
        }
    }
}

// ---------------- layer-1 propagate (fused e1+e2): 4 edges/iter ---------------
__global__ __launch_bounds__(256) void k_prop1f(const int* __restrict__ ptr1, const u16* __restrict__ csr1,
                                                const int* __restrict__ ptr2, const u16* __restrict__ csr2,
                                                const float* __restrict__ al,
                                                const uint2* __restrict__ xb2v,
                                                u16* __restrict__ out, int n) {
    __shared__ int sbuf[4][64];
    __shared__ __align__(16) float wbuf[4][64][4];
    int tid = threadIdx.x;
    int wv = tid >> 6, lane = tid & 63;
    int wid = (blockIdx.x * 256 + tid) >> 6;
    if (wid >= 2 * n) return;
    bool g2 = wid >= n;
    int node = g2 ? wid - n : wid;
    const int* ptr = g2 ? ptr2 : ptr1;
    const u16* csr = g2 ? csr2 : csr1;
    int doff = g2 ? 8 : 4;
    u16* outp = out + (size_t)node * 256 + (g2 ? 128 : 0);

    int b = ptr[node], e = ptr[node + 1];
    float4 adv = *(const float4*)(al + (size_t)node * 16 + doff);
    int l4 = lane & 15, q = lane >> 4;
    int h = l4 >> 2;

    float acc0 = 0.f, acc1 = 0.f, acc2 = 0.f, acc3 = 0.f;
    float acc4 = 0.f, acc5 = 0.f, acc6 = 0.f, acc7 = 0.f;
    float dn0 = 0.f, dn1 = 0.f, dn2 = 0.f, dn3 = 0.f;

    for (int cb = b; cb < e; cb += 64) {
        int cnt = min(64, e - cb);
        int s = 0;
        float w0 = 0.f, w1 = 0.f, w2 = 0.f, w3 = 0.f;
        if (lane < cnt) {
            s = csr[cb + lane];
            float4 av = *(const float4*)(al + (size_t)s * 16);
            float a0 = av.x + adv.x; a0 = a0 > 0.f ? a0 : 0.2f * a0; w0 = __expf(a0);
            float a1 = av.y + adv.y; a1 = a1 > 0.f ? a1 : 0.2f * a1; w1 = __expf(a1);
            float a2 = av.z + adv.z; a2 = a2 > 0.f ? a2 : 0.2f * a2; w2 = __expf(a2);
            float a3 = av.w + adv.w; a3 = a3 > 0.f ? a3 : 0.2f * a3; w3 = __expf(a3);
        }
        dn0 += w0; dn1 += w1; dn2 += w2; dn3 += w3;
        sbuf[wv][lane] = s;
        float4 wq4; wq4.x = w0; wq4.y = w1; wq4.z = w2; wq4.w = w3;
        *(float4*)&wbuf[wv][lane][0] = wq4;
        #pragma unroll 2
        for (int j = 0; j < cnt; j += 4) {
            int jq = j + q;
            int sj = sbuf[wv][jq];
            float wj = wbuf[wv][jq][h];
            uint2 pk = xb2v[(size_t)sj * 16 + l4];
            f32x2 c01 = __builtin_amdgcn_cvt_pk_f32_fp8(pk.x, false);
            f32x2 c23 = __builtin_amdgcn_cvt_pk_f32_fp8(pk.x, true);
            f32x2 c45 = __builtin_amdgcn_cvt_pk_f32_fp8(pk.y, false);
            f32x2 c67 = __builtin_amdgcn_cvt_pk_f32_fp8(pk.y, true);
            acc0 = fmaf(wj, c01.x, acc0);
            acc1 = fmaf(wj, c01.y, acc1);
            acc2 = fmaf(wj, c23.x, acc2);
            acc3 = fmaf(wj, c23.y, acc3);
            acc4 = fmaf(wj, c45.x, acc4);
            acc5 = fmaf(wj, c45.y, acc5);
            acc6 = fmaf(wj, c67.x, acc6);
            acc7 = fmaf(wj, c67.y, acc7);
        }
    }
    acc0 += __shfl_xor(acc0, 16); acc0 += __shfl_xor(acc0, 32);
    acc1 += __shfl_xor(acc1, 16); acc1 += __shfl_xor(acc1, 32);
    acc2 += __shfl_xor(acc2, 16); acc2 += __shfl_xor(acc2, 32);
    acc3 += __shfl_xor(acc3, 16); acc3 += __shfl_xor(acc3, 32);
    acc4 += __shfl_xor(acc4, 16); acc4 += __shfl_xor(acc4, 32);
    acc5 += __shfl_xor(acc5, 16); acc5 += __shfl_xor(acc5, 32);
    acc6 += __shfl_xor(acc6, 16); acc6 += __shfl_xor(acc6, 32);
    acc7 += __shfl_xor(acc7, 16); acc7 += __shfl_xor(acc7, 32);
    #pragma unroll
    for (int o = 32; o > 0; o >>= 1) {
        dn0 += __shfl_xor(dn0, o);
        dn1 += __shfl_xor(dn1, o);
        dn2 += __shfl_xor(dn2, o);
        dn3 += __shfl_xor(dn3, o);
    }
    if (lane < 16) {
        float dh = (h == 0) ? dn0 : (h == 1) ? dn1 : (h == 2) ? dn2 : dn3;
        float inv = 1.f / (dh + 1e-16f);
        float r0 = acc0 * inv, r1 = acc1 * inv, r2 = acc2 * inv, r3 = acc3 * inv;
        float r4 = acc4 * inv, r5 = acc5 * inv, r6 = acc6 * inv, r7 = acc7 * inv;
        r0 = r0 > 0.f ? r0 : __expf(r0) - 1.f;
        r1 = r1 > 0.f ? r1 : __expf(r1) - 1.f;
        r2 = r2 > 0.f ? r2 : __expf(r2) - 1.f;
        r3 = r3 > 0.f ? r3 : __expf(r3) - 1.f;
        r4 = r4 > 0.f ? r4 : __expf(r4) - 1.f;
        r5 = r5 > 0.f ? r5 : __expf(r5) - 1.f;
        r6 = r6 > 0.f ? r6 : __expf(r6) - 1.f;
        r7 = r7 > 0.f ? r7 : __expf(r7) - 1.f;
        uint4 st;
        st.x = (u32)f2bf(r0) | ((u32)f2bf(r1) << 16);
        st.y = (u32)f2bf(r2) | ((u32)f2bf(r3) << 16);
        st.z = (u32)f2bf(r4) | ((u32)f2bf(r5) << 16);
        st.w = (u32)f2bf(r6) | ((u32)f2bf(r7) << 16);
        *(uint4*)(outp + l4 * 8) = st;
    }
}

// ---------------- layer-2 propagate (fused e1+e2) ----------------
__global__ __launch_bounds__(256) void k_prop2f(const int* __restrict__ ptr1, const u16* __restrict__ csr1,
                                                const int* __restrict__ ptr2, const u16* __restrict__ csr2,
                                                const float* __restrict__ al,
                                                const uint2* __restrict__ xbv,
                                                float* __restrict__ out, int n) {
    __shared__ int2 swb[4][64];
    int tid = threadIdx.x;
    int wv = tid >> 6, lane = tid & 63;
    int wid = (blockIdx.x * 256 + tid) >> 6;
    if (wid >= 2 * n) return;
    bool g2 = wid >= n;
    int node = g2 ? wid - n : wid;
    const int* ptr = g2 ? ptr2 : ptr1;
    const u16* csr = g2 ? csr2 : csr1;
    int didx = g2 ? 2 : 1;
    float* outp = out + (size_t)node * 80 + (g2 ? 40 : 0);

    int b = ptr[node], e = ptr[node + 1];
    float ad = al[(size_t)node * 4 + didx];
    int g = lane / 10;
    int cp = lane - g * 10;
    bool act = g < 6;

    float acc0 = 0.f, acc1 = 0.f, acc2 = 0.f, acc3 = 0.f;
    float den = 0.f;

    for (int cb = b; cb < e; cb += 64) {
        int cnt = min(64, e - cb);
        int s = 0; float w = 0.f;
        if (lane < cnt) {
            s = csr[cb + lane];
            float a = al[(size_t)s * 4] + ad;
            a = a > 0.f ? a : 0.2f * a;
            w = __expf(a);
        }
        den += w;
        swb[wv][lane] = make_int2(s, __float_as_int(w));
        #pragma unroll 2
        for (int j = 0; j < cnt; j += 6) {
            int jj = j + g;
            bool valid = act && (jj < cnt);
            int2 sw = swb[wv][valid ? jj : 0];
            float wj = valid ? __int_as_float(sw.y) : 0.f;
            uint2 pk = xbv[(size_t)sw.x * 10 + cp];
            acc0 = fmaf(wj, bl(pk.x), acc0);
            acc1 = fmaf(wj, bh(pk.x), acc1);
            acc2 = fmaf(wj, bl(pk.y), acc2);
            acc3 = fmaf(wj, bh(pk.y), acc3);
        }
    }
    float t0;
    t0 = acc0 + __shfl(acc0, (lane + 30) & 63); acc0 = t0 + __shfl(t0, (lane + 10) & 63) + __shfl(t0, (lane + 20) & 63);
    t0 = acc1 + __shfl(acc1, (lane + 30) & 63); acc1 = t0 + __shfl(t0, (lane + 10) & 63) + __shfl(t0, (lane + 20) & 63);
    t0 = acc2 + __shfl(acc2, (lane + 30) & 63); acc2 = t0 + __shfl(t0, (lane + 10) & 63) + __shfl(t0, (lane + 20) & 63);
    t0 = acc3 + __shfl(acc3, (lane + 30) & 63); acc3 = t0 + __shfl(t0, (lane + 10) & 63) + __shfl(t0, (lane + 20) & 63);
    #pragma unroll
    for (int o = 32; o > 0; o >>= 1) den += __shfl_xor(den, o);
    if (lane < 10) {
        float inv = 1.f / (den + 1e-16f);
        float4 st; st.x = acc0 * inv; st.y = acc1 * inv; st.z = acc2 * inv; st.w = acc3 * inv;
        *(float4*)(outp + 4 * cp) = st;
    }
}

// ---------------- log_softmax ----------------
__global__ __launch_bounds__(256) void k_lsm(const float* __restrict__ h2, float* __restrict__ out, int n) {
    int wid = (blockIdx.x * blockDim.x + threadIdx.x) >> 6;
    int lane = threadIdx.x & 63;
    if (wid >= n) return;
    const float* row = h2 + (size_t)wid * 80;
    float v0 = row[lane];
    float v1 = (lane < 16) ? row[64 + lane] : -INFINITY;
    float m = fmaxf(v0, v1);
    for (int o = 32; o > 0; o >>= 1) m = fmaxf(m, __shfl_xor(m, o));
    float s = __expf(v0 - m) + ((lane < 16) ? __expf(v1 - m) : 0.f);
    for (int o = 32; o > 0; o >>= 1) s += __shfl_xor(s, o);
    float ls = m + logf(s);
    out[(size_t)wid * 80 + lane] = v0 - ls;
    if (lane < 16) out[(size_t)wid * 80 + 64 + lane] = v1 - ls;
}

// ---------------- launch ----------------

extern "C" void kernel_launch(void* const* d_in, const int* in_sizes, int n_in,
                              void* d_out, int out_size, void* d_ws, size_t ws_size,
                              hipStream_t stream) {
    const float* x       = (const float*)d_in[0];
    const int*   e1      = (const int*)d_in[1];
    const int*   e2      = (const int*)d_in[2];
    const float* W_src1  = (const float*)d_in[3];
    const float* W_dst1  = (const float*)d_in[4];
    const float* W_dst21 = (const float*)d_in[5];
    const float* a_src1  = (const float*)d_in[6];
    const float* a_dst1  = (const float*)d_in[7];
    const float* a_dst21 = (const float*)d_in[8];
    const float* W_src2  = (const float*)d_in[9];
    const float* W_dst2  = (const float*)d_in[10];
    const float* W_dst22 = (const float*)d_in[11];
    const float* a_src2  = (const float*)d_in[12];
    const float* a_dst2  = (const float*)d_in[13];
    const float* a_dst22 = (const float*)d_in[14];
    float* out = (float*)d_out;

    const int FIN = 500;
    int n  = in_sizes[0] / FIN;     // 50000
    int E1 = in_sizes[1] / 2;       // 300000
    int E2 = in_sizes[2] / 2;       // ~1.7M
    const int* src1 = e1, *dst1 = e1 + E1;
    const int* src2 = e2, *dst2 = e2 + E2;
    int nb = (n + 511) >> 9;        // 98

    char* w = (char*)d_ws;
    auto alloc = [&](size_t bytes) -> char* {
        char* p = w; w += (bytes + 255) & ~(size_t)255; return p;
    };
    u8*    xb1  = (u8*)alloc((size_t)n * 128);        // layer1 feats fp8 [n][128]
    float* alb1 = (float*)alloc((size_t)n * 16 * 4);  // [als(4)|ald1(4)|ald21(4)|pad]
    u16*   hbuf = (u16*)alloc((size_t)n * 256 * 2);   // elu(concat) hidden bf16 [n][256]
    u16*   xb2  = (u16*)alloc((size_t)n * 40 * 2);    // layer2 feats bf16 [n][40]
    float* alb2 = (float*)alloc((size_t)n * 4 * 4);   // [als|ald1|ald22|pad]
    float* h2   = (float*)alloc((size_t)n * 80 * 4);  // pre-logsoftmax fp32
    u16*   Bt1  = (u16*)alloc(144 * 512 * 2);
    u16*   Bt2  = (u16*)alloc(48 * 256 * 2);
    int* ptr1 = (int*)alloc((size_t)(n + 1) * 4);
    u16* csr1 = (u16*)alloc((size_t)E1 * 2);
    int* ptr2 = (int*)alloc((size_t)(n + 1) * 4);
    u16* csr2 = (u16*)alloc((size_t)E2 * 2);
    int* bcnt1  = (int*)alloc(NB * 4);   // NB*4 = 512 = 2x256 alignment -> bcnt2 adjacent
    int* bcnt2  = (int*)alloc(NB * 4);
    int* bbase1 = (int*)alloc((NB + 1) * 4);
    int* bbase2 = (int*)alloc((NB + 1) * 4);
    int* bcur1  = (int*)alloc(NB * 4);
    int* bcur2  = (int*)alloc(NB * 4);
    // partition scratch aliases h2 (dead until k_prop2f; stream-ordered)
    u32* part2 = (u32*)h2;
    u32* part1 = part2 + E2;

    int nblk1 = (E1 + 2047) / 2048;
    int nblk2 = (E2 + 2047) / 2048;

    // CSR build (bucket-first, fused pairs)
    hipMemsetAsync(bcnt1, 0, 2 * NB * 4, stream);   // bcnt1 + bcnt2 adjacent
    k_bhist2<<<nblk1 + nblk2, 256, 0, stream>>>(dst1, E1, bcnt1, dst2, E2, bcnt2, nblk1);
    k_bscan2<<<2, NB, 0, stream>>>(bcnt1, bbase1, bcur1, ptr1 + n,
                                   bcnt2, bbase2, bcur2, ptr2 + n, nb);
    k_part2<<<nblk1 + nblk2, 256, 0, stream>>>(src1, dst1, E1, bcur1, part1,
                                               src2, dst2, E2, bcur2, part2, nblk1);
    k_dhs2<<<2 * nb, 256, 0, stream>>>(part1, bbase1, ptr1, csr1,
                                       part2, bbase2, ptr2, csr2, n, nb);

    // weight prep (both layers, one kernel)
    k_build2<<<(144 * 512 + 48 * 256 + 255) / 256, 256, 0, stream>>>(
        W_src1, W_dst1, W_dst21, a_src1, a_dst1, a_dst21,
        W_src2, W_dst2, W_dst22, a_src2, a_dst2, a_dst22, Bt1, Bt2);

    // layer 1: fragment-split MFMA GEMM (2 waves/tile -> 2x occupancy)
    int nw = (n + 15) / 16;
    k_mgemm1<<<(2 * nw + 3) / 4, 256, 0, stream>>>(x, Bt1, xb1, alb1, n);

    // layer 1 propagate (both graphs, fused; + ELU), bf16 hidden out
    int pblocks2 = (2 * n + 3) / 4;
    k_prop1f<<<pblocks2, 256, 0, stream>>>(ptr1, csr1, ptr2, csr2, alb1,
                                           (const uint2*)xb1, hbuf, n);

    // layer 2: MFMA GEMM on bf16 hidden
    k_mgemm2<<<(nw + 3) / 4, 256, 0, stream>>>(hbuf, Bt2, xb2, alb2, n);

    // layer 2 propagate (both graphs, fused)
    k_prop2f<<<pblocks2, 256, 0, stream>>>(ptr1, csr1, ptr2, csr2, alb2,
                                           (const uint2*)xb2, h2, n);

    // log_softmax
    k_lsm<<<(n + 3) / 4, 256, 0, stream>>>(h2, out, n);
}

// Round 16
// 262.613 us; speedup vs baseline: 1.2128x; 1.0518x over previous
//
#include <hip/hip_runtime.h>
#include <hip/hip_bf16.h>
#include <math.h>

typedef unsigned short u16;
typedef unsigned int u32;
typedef unsigned char u8;
typedef __attribute__((ext_vector_type(8))) short short8;
typedef __attribute__((ext_vector_type(4))) float f32x4;
typedef __attribute__((ext_vector_type(2))) float f32x2;

#define NB 128  // bucket slots (actual buckets = ceil(n/512) = 98 for n=50000)

static __device__ __forceinline__ u16 f2bf(float f) {
    u32 u = __float_as_uint(f);
    u32 r = (u + 0x7fffu + ((u >> 16) & 1u)) >> 16;
    return (u16)r;
}
static __device__ __forceinline__ float bl(u32 u) { return __uint_as_float(u << 16); }
static __device__ __forceinline__ float bh(u32 u) { return __uint_as_float(u & 0xffff0000u); }

// ---------------- CSR build (fused pairs, bucket-first) ----------------

__global__ __launch_bounds__(256) void k_bhist2(const int* __restrict__ dst1, int E1,
                                                int* __restrict__ bcnt1,
                                                const int* __restrict__ dst2, int E2,
                                                int* __restrict__ bcnt2, int nblk1) {
    __shared__ int lh[NB];
    const int* dst; int E; int* bcnt; int bb;
    if (blockIdx.x < nblk1) { dst = dst1; E = E1; bcnt = bcnt1; bb = blockIdx.x; }
    else                    { dst = dst2; E = E2; bcnt = bcnt2; bb = blockIdx.x - nblk1; }
    int tid = threadIdx.x;
    int base = bb * 2048;
    for (int i = tid; i < NB; i += 256) lh[i] = 0;
    __syncthreads();
    int cnt = min(2048, E - base);
    #pragma unroll
    for (int k = 0; k < 8; k++) {
        int i = tid + k * 256;
        if (i < cnt) atomicAdd(&lh[dst[base + i] >> 9], 1);
    }
    __syncthreads();
    for (int i = tid; i < NB; i += 256) {
        int c = lh[i];
        if (c) atomicAdd(&bcnt[i], c);
    }
}

__global__ void k_bscan2(const int* __restrict__ bcnt1, int* __restrict__ bbase1,
                         int* __restrict__ bcur1, int* __restrict__ ptrN1,
                         const int* __restrict__ bcnt2, int* __restrict__ bbase2,
                         int* __restrict__ bcur2, int* __restrict__ ptrN2, int nb) {
    __shared__ int sh[NB];
    const int* bcnt = blockIdx.x ? bcnt2 : bcnt1;
    int* bbase = blockIdx.x ? bbase2 : bbase1;
    int* bcur  = blockIdx.x ? bcur2  : bcur1;
    int* ptrN  = blockIdx.x ? ptrN2  : ptrN1;
    int t = threadIdx.x;  // 128
    int v = (t < nb) ? bcnt[t] : 0;
    sh[t] = v;
    __syncthreads();
    for (int off = 1; off < NB; off <<= 1) {
        int val = sh[t];
        int add = (t >= off) ? sh[t - off] : 0;
        __syncthreads();
        sh[t] = val + add;
        __syncthreads();
    }
    int excl = sh[t] - v;
    if (t <= nb) bbase[t] = excl;
    if (t < nb) bcur[t] = excl;
    if (t == nb) *ptrN = excl;   // total = E
}

__global__ __launch_bounds__(256) void k_part2(const int* __restrict__ src1,
                                               const int* __restrict__ dst1, int E1,
                                               int* __restrict__ bcur1, u32* __restrict__ part1,
                                               const int* __restrict__ src2,
                                               const int* __restrict__ dst2, int E2,
                                               int* __restrict__ bcur2, u32* __restrict__ part2,
                                               int nblk1) {
    __shared__ int lh[NB];
    __shared__ int gb[NB];
    const int* src; const int* dst; int E; int* bcur; u32* part; int bb;
    if (blockIdx.x < nblk1) { src = src1; dst = dst1; E = E1; bcur = bcur1; part = part1; bb = blockIdx.x; }
    else                    { src = src2; dst = dst2; E = E2; bcur = bcur2; part = part2; bb = blockIdx.x - nblk1; }
    int tid = threadIdx.x;
    int base = bb * 2048;
    for (int i = tid; i < NB; i += 256) lh[i] = 0;
    __syncthreads();
    int cnt = min(2048, E - base);
    int bkt[8], rank[8]; u32 pk[8];
    #pragma unroll
    for (int k = 0; k < 8; k++) {
        int i = tid + k * 256;
        if (i < cnt) {
            int s = src[base + i], d = dst[base + i];
            int b = d >> 9;
            bkt[k] = b;
            pk[k] = ((u32)(d & 511) << 16) | (u32)s;
            rank[k] = atomicAdd(&lh[b], 1);
        } else bkt[k] = -1;
    }
    __syncthreads();
    for (int i = tid; i < NB; i += 256) {
        int c = lh[i];
        gb[i] = c ? atomicAdd(&bcur[i], c) : 0;
    }
    __syncthreads();
    #pragma unroll
    for (int k = 0; k < 8; k++)
        if (bkt[k] >= 0) part[gb[bkt[k]] + rank[k]] = pk[k];
}

// per-bucket: hist of dstLow9 + in-LDS scan -> ptr; then scatter slice -> csr16
__global__ __launch_bounds__(256) void k_dhs2(const u32* __restrict__ part1,
                                              const int* __restrict__ bbase1,
                                              int* __restrict__ ptrA1, u16* __restrict__ csr1,
                                              const u32* __restrict__ part2,
                                              const int* __restrict__ bbase2,
                                              int* __restrict__ ptrA2, u16* __restrict__ csr2,
                                              int n, int nbk) {
    __shared__ int hist[512];
    __shared__ int tsum[256];
    int b = blockIdx.x;
    const u32* part; const int* bbase; int* ptrArr; u16* csr;
    if (b < nbk) { part = part1; bbase = bbase1; ptrArr = ptrA1; csr = csr1; }
    else         { b -= nbk; part = part2; bbase = bbase2; ptrArr = ptrA2; csr = csr2; }
    int t = threadIdx.x;
    int lo = bbase[b], hi = bbase[b + 1];
    hist[t] = 0; hist[t + 256] = 0;
    __syncthreads();
    for (int i = lo + t; i < hi; i += 256)
        atomicAdd(&hist[(part[i] >> 16) & 511], 1);
    __syncthreads();
    int v0 = hist[2 * t], v1 = hist[2 * t + 1];
    tsum[t] = v0 + v1;
    __syncthreads();
    for (int off = 1; off < 256; off <<= 1) {
        int val = tsum[t];
        int add = (t >= off) ? tsum[t - off] : 0;
        __syncthreads();
        tsum[t] = val + add;
        __syncthreads();
    }
    int basep = lo + ((t == 0) ? 0 : tsum[t - 1]);
    int i0 = (b << 9) + 2 * t;
    if (i0 < n)     ptrArr[i0] = basep;
    if (i0 + 1 < n) ptrArr[i0 + 1] = basep + v0;
    __syncthreads();
    hist[2 * t] = basep;             // cursors
    hist[2 * t + 1] = basep + v0;
    __syncthreads();
    for (int i = lo + t; i < hi; i += 256) {
        u32 pk = part[i];
        int pos = atomicAdd(&hist[(pk >> 16) & 511], 1);
        csr[pos] = (u16)(pk & 0xffffu);
    }
}

// ---------------- weight prep (both transposed bf16 B matrices, one kernel) ---
__global__ void k_build2(const float* __restrict__ Ws1, const float* __restrict__ Wd1,
                         const float* __restrict__ Wd21, const float* __restrict__ as1,
                         const float* __restrict__ ad1, const float* __restrict__ ad21,
                         const float* __restrict__ Ws2, const float* __restrict__ Wd2,
                         const float* __restrict__ Wd22, const float* __restrict__ as2,
                         const float* __restrict__ ad2, const float* __restrict__ ad22,
                         u16* __restrict__ Bt1, u16* __restrict__ Bt2) {
    int t = blockIdx.x * blockDim.x + threadIdx.x;
    if (t < 144 * 512) {
        int nn = t >> 9, k = t & 511;
        float v = 0.f;
        if (k < 500) {
            if (nn < 128) v = Ws1[k * 128 + nn];
            else if (nn < 140) {
                int q = nn - 128; int h = q & 3;
                const float* W; const float* a;
                if (q < 4)      { W = Ws1;  a = as1; }
                else if (q < 8) { W = Wd1;  a = ad1;  }
                else            { W = Wd21; a = ad21; }
                float s = 0.f;
                #pragma unroll 8
                for (int c = 0; c < 32; c++) s += W[k * 128 + h * 32 + c] * a[h * 32 + c];
                v = s;
            }
        }
        Bt1[t] = f2bf(v);
    } else {
        t -= 144 * 512;
        if (t >= 48 * 256) return;
        int nn = t >> 8, k = t & 255;
        float v = 0.f;
        if (nn < 40) v = Ws2[k * 40 + nn];
        else if (nn < 43) {
            const float* a = (nn == 40) ? as2 : (nn == 41) ? ad2 : ad22;
            const float* W = Ws2;
            if (nn == 41) W = Wd2; else if (nn == 42) W = Wd22;
            float s = 0.f;
            #pragma unroll 8
            for (int c = 0; c < 40; c++) s += W[k * 40 + c] * a[c];
            v = s;
        }
        Bt2[t] = f2bf(v);
    }
}

// ---------------- MFMA GEMM layer 1: B LDS-resident in 4 K-phases -------------
// (best-measured form: 1 wave per 16-row tile, ~62 us)
__global__ __launch_bounds__(256) void k_mgemm1(const float* __restrict__ A,
                                                const u16* __restrict__ Bt,
                                                u8* __restrict__ xb,
                                                float* __restrict__ alb, int M) {
    __shared__ __align__(16) u16 Bs[144][136];
    int tid = threadIdx.x;
    int wv = tid >> 6, lane = tid & 63;
    int l15 = lane & 15, k8 = lane >> 4;
    int wid = blockIdx.x * 4 + wv;
    int nw = (M + 15) >> 4;
    bool active = wid < nw;
    int rowBlk = wid * 16;
    int arow = rowBlk + l15;
    bool rowOK = active && (arow < M);
    const float* Ap0 = A + (size_t)arow * 500;

    f32x4 acc[9];
    #pragma unroll
    for (int t = 0; t < 9; t++) acc[t] = (f32x4){0.f, 0.f, 0.f, 0.f};

    for (int q = 0; q < 4; q++) {
        if (q) __syncthreads();
        for (int idx = tid; idx < 2304; idx += 256) {
            int row = idx >> 4, c = (idx & 15) * 8;
            *(uint4*)&Bs[row][c] = *(const uint4*)&Bt[row * 512 + q * 128 + c];
        }
        __syncthreads();
        #pragma unroll
        for (int ki = 0; ki < 4; ki++) {
            int kg = q * 128 + ki * 32 + k8 * 8;
            float v[8];
            if (rowOK && (kg + 8 <= 500)) {
                float4 p0 = *(const float4*)(Ap0 + kg);
                float4 p1 = *(const float4*)(Ap0 + kg + 4);
                v[0] = p0.x; v[1] = p0.y; v[2] = p0.z; v[3] = p0.w;
                v[4] = p1.x; v[5] = p1.y; v[6] = p1.z; v[7] = p1.w;
            } else {
                #pragma unroll
                for (int i = 0; i < 8; i++)
                    v[i] = (rowOK && kg + i < 500) ? Ap0[kg + i] : 0.f;
            }
            short8 af;
            ((u32*)&af)[0] = (u32)f2bf(v[0]) | ((u32)f2bf(v[1]) << 16);
            ((u32*)&af)[1] = (u32)f2bf(v[2]) | ((u32)f2bf(v[3]) << 16);
            ((u32*)&af)[2] = (u32)f2bf(v[4]) | ((u32)f2bf(v[5]) << 16);
            ((u32*)&af)[3] = (u32)f2bf(v[6]) | ((u32)f2bf(v[7]) << 16);
            int kl = ki * 32 + k8 * 8;
            #pragma unroll
            for (int t = 0; t < 9; t++) {
                short8 bf = *(const short8*)&Bs[t * 16 + l15][kl];
                acc[t] = __builtin_amdgcn_mfma_f32_16x16x32_bf16(af, bf, acc[t], 0, 0, 0);
            }
        }
    }
    if (active) {
        #pragma unroll
        for (int t = 0; t < 9; t++) {
            #pragma unroll
            for (int rr = 0; rr < 4; rr++) {
                int grow = rowBlk + k8 * 4 + rr;
                if (grow < M) {
                    if (t < 8) {
                        u32 p8 = __builtin_amdgcn_cvt_pk_fp8_f32(acc[t][rr], acc[t][rr], 0, false);
                        xb[(size_t)grow * 128 + t * 16 + l15] = (u8)(p8 & 0xffu);
                    } else if (l15 < 12) {
                        alb[(size_t)grow * 16 + l15] = acc[t][rr];
                    }
                }
            }
        }
    }
}

// ---------------- MFMA GEMM layer 2: whole B LDS-resident, 1 barrier ----------
__global__ __launch_bounds__(256) void k_mgemm2(const u16* __restrict__ A,
                                                const u16* __restrict__ Bt,
                                                u16* __restrict__ xb,
                                                float* __restrict__ alb, int M) {
    __shared__ __align__(16) u16 Bs[48][264];
    int tid = threadIdx.x;
    int wv = tid >> 6, lane = tid & 63;
    int l15 = lane & 15, k8 = lane >> 4;
    int wid = blockIdx.x * 4 + wv;
    int nw = (M + 15) >> 4;
    bool active = wid < nw;
    int rowBlk = wid * 16;
    int arow = rowBlk + l15;
    bool rowOK = active && (arow < M);
    const u16* Ap0 = A + (size_t)arow * 256;

    for (int idx = tid; idx < 1536; idx += 256) {
        int row = idx >> 5, c = (idx & 31) * 8;
        *(uint4*)&Bs[row][c] = *(const uint4*)&Bt[row * 256 + c];
    }
    __syncthreads();

    f32x4 acc[3];
    #pragma unroll
    for (int t = 0; t < 3; t++) acc[t] = (f32x4){0.f, 0.f, 0.f, 0.f};

    #pragma unroll
    for (int ki = 0; ki < 8; ki++) {
        int k0 = ki * 32 + k8 * 8;
        short8 af = {0, 0, 0, 0, 0, 0, 0, 0};
        if (rowOK) af = *(const short8*)(Ap0 + k0);
        #pragma unroll
        for (int t = 0; t < 3; t++) {
            short8 bf = *(const short8*)&Bs[t * 16 + l15][k0];
            acc[t] = __builtin_amdgcn_mfma_f32_16x16x32_bf16(af, bf, acc[t], 0, 0, 0);
        }
    }
    if (active) {
        #pragma unroll
        for (int t = 0; t < 3; t++) {
            #pragma unroll
            for (int rr = 0; rr < 4; rr++) {
                int grow = rowBlk + k8 * 4 + rr;
                if (grow < M) {
                    int col = t * 16 + l15;
                    if (col < 40) xb[(size_t)grow * 40 + col] = f2bf(acc[t][rr]);
                    else if (col < 43) alb[(size_t)grow * 4 + (col - 40)] = acc[t][rr];
                }
            }
        }
    }
}

// ---------------- layer-1 propagate (fused e1+e2): 4 edges/iter ---------------
__global__ __launch_bounds__(256) void k_prop1f(const int* __restrict__ ptr1, const u16* __restrict__ csr1,
                                                const int* __restrict__ ptr2, const u16* __restrict__ csr2,
                                                const float* __restrict__ al,
                                                const uint2* __restrict__ xb2v,
                                                u16* __restrict__ out, int n) {
    __shared__ int sbuf[4][64];
    __shared__ __align__(16) float wbuf[4][64][4];
    int tid = threadIdx.x;
    int wv = tid >> 6, lane = tid & 63;
    int wid = (blockIdx.x * 256 + tid) >> 6;
    if (wid >= 2 * n) return;
    bool g2 = wid >= n;
    int node = g2 ? wid - n : wid;
    const int* ptr = g2 ? ptr2 : ptr1;
    const u16* csr = g2 ? csr2 : csr1;
    int doff = g2 ? 8 : 4;
    u16* outp = out + (size_t)node * 256 + (g2 ? 128 : 0);

    int b = ptr[node], e = ptr[node + 1];
    float4 adv = *(const float4*)(al + (size_t)node * 16 + doff);
    int l4 = lane & 15, q = lane >> 4;
    int h = l4 >> 2;

    float acc0 = 0.f, acc1 = 0.f, acc2 = 0.f, acc3 = 0.f;
    float acc4 = 0.f, acc5 = 0.f, acc6 = 0.f, acc7 = 0.f;
    float dn0 = 0.f, dn1 = 0.f, dn2 = 0.f, dn3 = 0.f;

    for (int cb = b; cb < e; cb += 64) {
        int cnt = min(64, e - cb);
        int s = 0;
        float w0 = 0.f, w1 = 0.f, w2 = 0.f, w3 = 0.f;
        if (lane < cnt) {
            s = csr[cb + lane];
            float4 av = *(const float4*)(al + (size_t)s * 16);
            float a0 = av.x + adv.x; a0 = a0 > 0.f ? a0 : 0.2f * a0; w0 = __expf(a0);
            float a1 = av.y + adv.y; a1 = a1 > 0.f ? a1 : 0.2f * a1; w1 = __expf(a1);
            float a2 = av.z + adv.z; a2 = a2 > 0.f ? a2 : 0.2f * a2; w2 = __expf(a2);
            float a3 = av.w + adv.w; a3 = a3 > 0.f ? a3 : 0.2f * a3; w3 = __expf(a3);
        }
        dn0 += w0; dn1 += w1; dn2 += w2; dn3 += w3;
        sbuf[wv][lane] = s;
        float4 wq4; wq4.x = w0; wq4.y = w1; wq4.z = w2; wq4.w = w3;
        *(float4*)&wbuf[wv][lane][0] = wq4;
        #pragma unroll 2
        for (int j = 0; j < cnt; j += 4) {
            int jq = j + q;
            int sj = sbuf[wv][jq];
            float wj = wbuf[wv][jq][h];
            uint2 pk = xb2v[(size_t)sj * 16 + l4];
            f32x2 c01 = __builtin_amdgcn_cvt_pk_f32_fp8(pk.x, false);
            f32x2 c23 = __builtin_amdgcn_cvt_pk_f32_fp8(pk.x, true);
            f32x2 c45 = __builtin_amdgcn_cvt_pk_f32_fp8(pk.y, false);
            f32x2 c67 = __builtin_amdgcn_cvt_pk_f32_fp8(pk.y, true);
            acc0 = fmaf(wj, c01.x, acc0);
            acc1 = fmaf(wj, c01.y, acc1);
            acc2 = fmaf(wj, c23.x, acc2);
            acc3 = fmaf(wj, c23.y, acc3);
            acc4 = fmaf(wj, c45.x, acc4);
            acc5 = fmaf(wj, c45.y, acc5);
            acc6 = fmaf(wj, c67.x, acc6);
            acc7 = fmaf(wj, c67.y, acc7);
        }
    }
    acc0 += __shfl_xor(acc0, 16); acc0 += __shfl_xor(acc0, 32);
    acc1 += __shfl_xor(acc1, 16); acc1 += __shfl_xor(acc1, 32);
    acc2 += __shfl_xor(acc2, 16); acc2 += __shfl_xor(acc2, 32);
    acc3 += __shfl_xor(acc3, 16); acc3 += __shfl_xor(acc3, 32);
    acc4 += __shfl_xor(acc4, 16); acc4 += __shfl_xor(acc4, 32);
    acc5 += __shfl_xor(acc5, 16); acc5 += __shfl_xor(acc5, 32);
    acc6 += __shfl_xor(acc6, 16); acc6 += __shfl_xor(acc6, 32);
    acc7 += __shfl_xor(acc7, 16); acc7 += __shfl_xor(acc7, 32);
    #pragma unroll
    for (int o = 32; o > 0; o >>= 1) {
        dn0 += __shfl_xor(dn0, o);
        dn1 += __shfl_xor(dn1, o);
        dn2 += __shfl_xor(dn2, o);
        dn3 += __shfl_xor(dn3, o);
    }
    if (lane < 16) {
        float dh = (h == 0) ? dn0 : (h == 1) ? dn1 : (h == 2) ? dn2 : dn3;
        float inv = 1.f / (dh + 1e-16f);
        float r0 = acc0 * inv, r1 = acc1 * inv, r2 = acc2 * inv, r3 = acc3 * inv;
        float r4 = acc4 * inv, r5 = acc5 * inv, r6 = acc6 * inv, r7 = acc7 * inv;
        r0 = r0 > 0.f ? r0 : __expf(r0) - 1.f;
        r1 = r1 > 0.f ? r1 : __expf(r1) - 1.f;
        r2 = r2 > 0.f ? r2 : __expf(r2) - 1.f;
        r3 = r3 > 0.f ? r3 : __expf(r3) - 1.f;
        r4 = r4 > 0.f ? r4 : __expf(r4) - 1.f;
        r5 = r5 > 0.f ? r5 : __expf(r5) - 1.f;
        r6 = r6 > 0.f ? r6 : __expf(r6) - 1.f;
        r7 = r7 > 0.f ? r7 : __expf(r7) - 1.f;
        uint4 st;
        st.x = (u32)f2bf(r0) | ((u32)f2bf(r1) << 16);
        st.y = (u32)f2bf(r2) | ((u32)f2bf(r3) << 16);
        st.z = (u32)f2bf(r4) | ((u32)f2bf(r5) << 16);
        st.w = (u32)f2bf(r6) | ((u32)f2bf(r7) << 16);
        *(uint4*)(outp + l4 * 8) = st;
    }
}

// ---------------- layer-2 propagate (fused e1+e2) ----------------
__global__ __launch_bounds__(256) void k_prop2f(const int* __restrict__ ptr1, const u16* __restrict__ csr1,
                                                const int* __restrict__ ptr2, const u16* __restrict__ csr2,
                                                const float* __restrict__ al,
                                                const uint2* __restrict__ xbv,
                                                float* __restrict__ out, int n) {
    __shared__ int2 swb[4][64];
    int tid = threadIdx.x;
    int wv = tid >> 6, lane = tid & 63;
    int wid = (blockIdx.x * 256 + tid) >> 6;
    if (wid >= 2 * n) return;
    bool g2 = wid >= n;
    int node = g2 ? wid - n : wid;
    const int* ptr = g2 ? ptr2 : ptr1;
    const u16* csr = g2 ? csr2 : csr1;
    int didx = g2 ? 2 : 1;
    float* outp = out + (size_t)node * 80 + (g2 ? 40 : 0);

    int b = ptr[node], e = ptr[node + 1];
    float ad = al[(size_t)node * 4 + didx];
    int g = lane / 10;
    int cp = lane - g * 10;
    bool act = g < 6;

    float acc0 = 0.f, acc1 = 0.f, acc2 = 0.f, acc3 = 0.f;
    float den = 0.f;

    for (int cb = b; cb < e; cb += 64) {
        int cnt = min(64, e - cb);
        int s = 0; float w = 0.f;
        if (lane < cnt) {
            s = csr[cb + lane];
            float a = al[(size_t)s * 4] + ad;
            a = a > 0.f ? a : 0.2f * a;
            w = __expf(a);
        }
        den += w;
        swb[wv][lane] = make_int2(s, __float_as_int(w));
        #pragma unroll 2
        for (int j = 0; j < cnt; j += 6) {
            int jj = j + g;
            bool valid = act && (jj < cnt);
            int2 sw = swb[wv][valid ? jj : 0];
            float wj = valid ? __int_as_float(sw.y) : 0.f;
            uint2 pk = xbv[(size_t)sw.x * 10 + cp];
            acc0 = fmaf(wj, bl(pk.x), acc0);
            acc1 = fmaf(wj, bh(pk.x), acc1);
            acc2 = fmaf(wj, bl(pk.y), acc2);
            acc3 = fmaf(wj, bh(pk.y), acc3);
        }
    }
    float t0;
    t0 = acc0 + __shfl(acc0, (lane + 30) & 63); acc0 = t0 + __shfl(t0, (lane + 10) & 63) + __shfl(t0, (lane + 20) & 63);
    t0 = acc1 + __shfl(acc1, (lane + 30) & 63); acc1 = t0 + __shfl(t0, (lane + 10) & 63) + __shfl(t0, (lane + 20) & 63);
    t0 = acc2 + __shfl(acc2, (lane + 30) & 63); acc2 = t0 + __shfl(t0, (lane + 10) & 63) + __shfl(t0, (lane + 20) & 63);
    t0 = acc3 + __shfl(acc3, (lane + 30) & 63); acc3 = t0 + __shfl(t0, (lane + 10) & 63) + __shfl(t0, (lane + 20) & 63);
    #pragma unroll
    for (int o = 32; o > 0; o >>= 1) den += __shfl_xor(den, o);
    if (lane < 10) {
        float inv = 1.f / (den + 1e-16f);
        float4 st; st.x = acc0 * inv; st.y = acc1 * inv; st.z = acc2 * inv; st.w = acc3 * inv;
        *(float4*)(outp + 4 * cp) = st;
    }
}

// ---------------- log_softmax ----------------
__global__ __launch_bounds__(256) void k_lsm(const float* __restrict__ h2, float* __restrict__ out, int n) {
    int wid = (blockIdx.x * blockDim.x + threadIdx.x) >> 6;
    int lane = threadIdx.x & 63;
    if (wid >= n) return;
    const float* row = h2 + (size_t)wid * 80;
    float v0 = row[lane];
    float v1 = (lane < 16) ? row[64 + lane] : -INFINITY;
    float m = fmaxf(v0, v1);
    for (int o = 32; o > 0; o >>= 1) m = fmaxf(m, __shfl_xor(m, o));
    float s = __expf(v0 - m) + ((lane < 16) ? __expf(v1 - m) : 0.f);
    for (int o = 32; o > 0; o >>= 1) s += __shfl_xor(s, o);
    float ls = m + logf(s);
    out[(size_t)wid * 80 + lane] = v0 - ls;
    if (lane < 16) out[(size_t)wid * 80 + 64 + lane] = v1 - ls;
}

// ---------------- launch ----------------

extern "C" void kernel_launch(void* const* d_in, const int* in_sizes, int n_in,
                              void* d_out, int out_size, void* d_ws, size_t ws_size,
                              hipStream_t stream) {
    const float* x       = (const float*)d_in[0];
    const int*   e1      = (const int*)d_in[1];
    const int*   e2      = (const int*)d_in[2];
    const float* W_src1  = (const float*)d_in[3];
    const float* W_dst1  = (const float*)d_in[4];
    const float* W_dst21 = (const float*)d_in[5];
    const float* a_src1  = (const float*)d_in[6];
    const float* a_dst1  = (const float*)d_in[7];
    const float* a_dst21 = (const float*)d_in[8];
    const float* W_src2  = (const float*)d_in[9];
    const float* W_dst2  = (const float*)d_in[10];
    const float* W_dst22 = (const float*)d_in[11];
    const float* a_src2  = (const float*)d_in[12];
    const float* a_dst2  = (const float*)d_in[13];
    const float* a_dst22 = (const float*)d_in[14];
    float* out = (float*)d_out;

    const int FIN = 500;
    int n  = in_sizes[0] / FIN;     // 50000
    int E1 = in_sizes[1] / 2;       // 300000
    int E2 = in_sizes[2] / 2;       // ~1.7M
    const int* src1 = e1, *dst1 = e1 + E1;
    const int* src2 = e2, *dst2 = e2 + E2;
    int nb = (n + 511) >> 9;        // 98

    char* w = (char*)d_ws;
    auto alloc = [&](size_t bytes) -> char* {
        char* p = w; w += (bytes + 255) & ~(size_t)255; return p;
    };
    u8*    xb1  = (u8*)alloc((size_t)n * 128);        // layer1 feats fp8 [n][128]
    float* alb1 = (float*)alloc((size_t)n * 16 * 4);  // [als(4)|ald1(4)|ald21(4)|pad]
    u16*   hbuf = (u16*)alloc((size_t)n * 256 * 2);   // elu(concat) hidden bf16 [n][256]
    u16*   xb2  = (u16*)alloc((size_t)n * 40 * 2);    // layer2 feats bf16 [n][40]
    float* alb2 = (float*)alloc((size_t)n * 4 * 4);   // [als|ald1|ald22|pad]
    float* h2   = (float*)alloc((size_t)n * 80 * 4);  // pre-logsoftmax fp32
    u16*   Bt1  = (u16*)alloc(144 * 512 * 2);
    u16*   Bt2  = (u16*)alloc(48 * 256 * 2);
    int* ptr1 = (int*)alloc((size_t)(n + 1) * 4);
    u16* csr1 = (u16*)alloc((size_t)E1 * 2);
    int* ptr2 = (int*)alloc((size_t)(n + 1) * 4);
    u16* csr2 = (u16*)alloc((size_t)E2 * 2);
    int* bcnt1  = (int*)alloc(NB * 4);   // NB*4 = 512 -> bcnt2 adjacent
    int* bcnt2  = (int*)alloc(NB * 4);
    int* bbase1 = (int*)alloc((NB + 1) * 4);
    int* bbase2 = (int*)alloc((NB + 1) * 4);
    int* bcur1  = (int*)alloc(NB * 4);
    int* bcur2  = (int*)alloc(NB * 4);
    // partition scratch aliases h2 (dead until k_prop2f; stream-ordered)
    u32* part2 = (u32*)h2;
    u32* part1 = part2 + E2;

    int nblk1 = (E1 + 2047) / 2048;
    int nblk2 = (E2 + 2047) / 2048;

    // CSR build (bucket-first, fused pairs)
    hipMemsetAsync(bcnt1, 0, 2 * NB * 4, stream);   // bcnt1 + bcnt2 adjacent
    k_bhist2<<<nblk1 + nblk2, 256, 0, stream>>>(dst1, E1, bcnt1, dst2, E2, bcnt2, nblk1);
    k_bscan2<<<2, NB, 0, stream>>>(bcnt1, bbase1, bcur1, ptr1 + n,
                                   bcnt2, bbase2, bcur2, ptr2 + n, nb);
    k_part2<<<nblk1 + nblk2, 256, 0, stream>>>(src1, dst1, E1, bcur1, part1,
                                               src2, dst2, E2, bcur2, part2, nblk1);
    k_dhs2<<<2 * nb, 256, 0, stream>>>(part1, bbase1, ptr1, csr1,
                                       part2, bbase2, ptr2, csr2, n, nb);

    // weight prep (both layers, one kernel)
    k_build2<<<(144 * 512 + 48 * 256 + 255) / 256, 256, 0, stream>>>(
        W_src1, W_dst1, W_dst21, a_src1, a_dst1, a_dst21,
        W_src2, W_dst2, W_dst22, a_src2, a_dst2, a_dst22, Bt1, Bt2);

    // layer 1: MFMA GEMM (phase-staged B, 1 wave/tile — best measured)
    int nw = (n + 15) / 16;
    k_mgemm1<<<(nw + 3) / 4, 256, 0, stream>>>(x, Bt1, xb1, alb1, n);

    // layer 1 propagate (both graphs, fused; + ELU), fp8->bf16 hidden out
    int pblocks2 = (2 * n + 3) / 4;
    k_prop1f<<<pblocks2, 256, 0, stream>>>(ptr1, csr1, ptr2, csr2, alb1,
                                           (const uint2*)xb1, hbuf, n);

    // layer 2: MFMA GEMM on bf16 hidden
    k_mgemm2<<<(nw + 3) / 4, 256, 0, stream>>>(hbuf, Bt2, xb2, alb2, n);

    // layer 2 propagate (both graphs, fused)
    k_prop2f<<<pblocks2, 256, 0, stream>>>(ptr1, csr1, ptr2, csr2, alb2,
                                           (const uint2*)xb2, h2, n);

    // log_softmax
    k_lsm<<<(n + 3) / 4, 256, 0, stream>>>(h2, out, n);
}